// Round 2
// baseline (457.025 us; speedup 1.0000x reference)
//
#include <hip/hip_runtime.h>
#include <hip/hip_bf16.h>

typedef unsigned short u16;
typedef unsigned int u32;

__device__ __forceinline__ float bfu(u16 u) { return __uint_as_float(((u32)u) << 16); }
__device__ __forceinline__ u16 fbf(float f) {
  __hip_bfloat16 h = __float2bfloat16(f);
  return *reinterpret_cast<u16*>(&h);
}
__device__ __forceinline__ float softplusf(float z) {
  return (z > 20.f) ? z : log1pf(__expf(z));
}

// ---- K1: in_proj GEMM: out[b,o,l] = sum_c W[o,c] * x[b,c,l]  (f32 in, bf16 out)
__global__ __launch_bounds__(256) void k_inproj(const float* __restrict__ X,
                                                const float* __restrict__ W,
                                                u16* __restrict__ out) {
  __shared__ __align__(16) u16 Wt[128 * 136];  // [c][o]
  __shared__ __align__(16) u16 Xs[128 * 72];   // [c][p]
  int tid = threadIdx.x;
  int b = blockIdx.x >> 8;
  int l0 = (blockIdx.x & 255) << 6;
  for (int i = 0; i < 64; ++i) {
    int lin = (i << 8) + tid;
    int o = lin >> 7, c = lin & 127;
    Wt[c * 136 + o] = fbf(W[lin]);
  }
  for (int i = 0; i < 32; ++i) {
    int lin = (i << 8) + tid;
    int c = lin >> 6, p = lin & 63;
    Xs[c * 72 + p] = fbf(X[(((b << 7) + c) << 14) + l0 + p]);
  }
  __syncthreads();
  int tx = tid & 15, ty = tid >> 4;
  int o0 = tx << 3, p0 = ty << 2;
  float acc[8][4] = {};
  for (int c = 0; c < 128; ++c) {
    uint4 aw = *(const uint4*)&Wt[c * 136 + o0];
    uint2 bw = *(const uint2*)&Xs[c * 72 + p0];
    float a[8], bv[4];
    a[0] = __uint_as_float(aw.x << 16); a[1] = __uint_as_float(aw.x & 0xffff0000u);
    a[2] = __uint_as_float(aw.y << 16); a[3] = __uint_as_float(aw.y & 0xffff0000u);
    a[4] = __uint_as_float(aw.z << 16); a[5] = __uint_as_float(aw.z & 0xffff0000u);
    a[6] = __uint_as_float(aw.w << 16); a[7] = __uint_as_float(aw.w & 0xffff0000u);
    bv[0] = __uint_as_float(bw.x << 16); bv[1] = __uint_as_float(bw.x & 0xffff0000u);
    bv[2] = __uint_as_float(bw.y << 16); bv[3] = __uint_as_float(bw.y & 0xffff0000u);
#pragma unroll
    for (int i = 0; i < 8; ++i)
#pragma unroll
      for (int j = 0; j < 4; ++j) acc[i][j] = fmaf(a[i], bv[j], acc[i][j]);
  }
#pragma unroll
  for (int i = 0; i < 8; ++i) {
    ushort4 sv;
    sv.x = fbf(acc[i][0]); sv.y = fbf(acc[i][1]);
    sv.z = fbf(acc[i][2]); sv.w = fbf(acc[i][3]);
    *(ushort4*)&out[(((b << 7) + o0 + i) << 14) + l0 + p0] = sv;
  }
}

// ---- K2/K3a: depthwise 3x3 conv (bf16 in/out, f32 weights), optional SiLU --
__global__ __launch_bounds__(256) void k_dwconv(const u16* __restrict__ in,
                                                const float* __restrict__ w9,
                                                const float* __restrict__ bias,
                                                u16* __restrict__ out, int act) {
  int blk = blockIdx.x;
  int bc = blk >> 6;
  int c = bc & 127;
  int h = ((blk & 63) << 1) + (threadIdx.x >> 7);
  int w = threadIdx.x & 127;
  float wt[9];
#pragma unroll
  for (int k = 0; k < 9; ++k) wt[k] = w9[c * 9 + k];
  const u16* base = in + ((long)bc << 14);
  float acc = bias[c];
#pragma unroll
  for (int ky = -1; ky <= 1; ++ky) {
    int y = h + ky;
    if ((unsigned)y < 128u) {
      const u16* row = base + (y << 7);
#pragma unroll
      for (int kx = -1; kx <= 1; ++kx) {
        int x = w + kx;
        if ((unsigned)x < 128u) acc = fmaf(wt[(ky + 1) * 3 + kx + 1], bfu(row[x]), acc);
      }
    }
  }
  if (act) acc = acc / (1.f + __expf(-acc));
  out[((long)bc << 14) + (h << 7) + w] = fbf(acc);
}

// ---- K3b: per-pixel LN(channels) + GELU + offset projection (16 outputs) ---
__global__ __launch_bounds__(256) void k_offset(const u16* __restrict__ x1,
                                                const float* __restrict__ g,
                                                const float* __restrict__ bt,
                                                const float* __restrict__ offw,
                                                const float* __restrict__ offb,
                                                float* __restrict__ offs) {
  __shared__ float Wo[16 * 128];
  __shared__ float gs[128], bs[128];
  int tid = threadIdx.x;
  if (tid < 128) { gs[tid] = g[tid]; bs[tid] = bt[tid]; }
  for (int i = 0; i < 8; ++i) { int idx = (i << 8) + tid; Wo[idx] = offw[idx]; }
  __syncthreads();
  int pg = (blockIdx.x << 8) + tid;
  int b = pg >> 14, l = pg & 16383;
  const u16* px = x1 + ((long)b << 21) + l;
  float s = 0.f, ss = 0.f;
  for (int c = 0; c < 128; ++c) { float v = bfu(px[(long)c << 14]); s += v; ss = fmaf(v, v, ss); }
  float mean = s * (1.f / 128.f);
  float var = ss * (1.f / 128.f) - mean * mean;
  float rstd = rsqrtf(var + 1e-6f);
  float acc[16];
#pragma unroll
  for (int j = 0; j < 16; ++j) acc[j] = offb[j];
  for (int c = 0; c < 128; ++c) {
    float v = bfu(px[(long)c << 14]);
    float xn = fmaf((v - mean) * rstd, gs[c], bs[c]);
    float ge = 0.5f * xn * (1.f + erff(xn * 0.70710678118f));
#pragma unroll
    for (int j = 0; j < 16; ++j) acc[j] = fmaf(Wo[j * 128 + c], ge, acc[j]);
  }
  float* po = offs + ((long)pg << 4);
#pragma unroll
  for (int j = 0; j < 4; ++j)
    *(float4*)&po[j << 2] = make_float4(acc[4 * j], acc[4 * j + 1], acc[4 * j + 2], acc[4 * j + 3]);
}

// ---- K4: DCN bilinear gather + x_proj (10x128) + dt_w (128x8) fused --------
__global__ __launch_bounds__(256) void k_dcn(const u16* __restrict__ xc,
                                             const float* __restrict__ offs,
                                             const float* __restrict__ xpw,
                                             const float* __restrict__ dtw,
                                             u16* __restrict__ xs,
                                             u16* __restrict__ dts,
                                             float* __restrict__ Bsb,
                                             float* __restrict__ Csb) {
  __shared__ float xds[32 * 132];
  __shared__ float xdbl[32 * 12];
  __shared__ float xpws[1280];
  __shared__ float dtws[1024];
  int tid = threadIdx.x;
  for (int i = 0; i < 5; ++i) { int idx = (i << 8) + tid; if (idx < 1280) xpws[idx] = xpw[idx]; }
  for (int i = 0; i < 4; ++i) { int idx = (i << 8) + tid; dtws[idx] = dtw[idx]; }
  int blk = blockIdx.x;
  int b = blk >> 9;
  int l0 = (blk & 511) << 5;
  int p = tid >> 3, gg = tid & 7;
  int l = l0 + p, hh = l >> 7, ww = l & 127;
  float2 off = *(const float2*)&offs[(((long)(b << 14) + l) << 4) + (gg << 1)];
  float px = (float)ww + off.x, py = (float)hh + off.y;
  float x0f = floorf(px), y0f = floorf(py);
  float wx = px - x0f, wy = py - y0f;
  int ix = (int)x0f, iy = (int)y0f;
  float acc[16];
#pragma unroll
  for (int ch = 0; ch < 16; ++ch) acc[ch] = 0.f;
  const u16* gbase = xc + (((long)(b << 7) + (gg << 4)) << 14);
  int xi[4] = {ix, ix + 1, ix, ix + 1};
  int yi[4] = {iy, iy, iy + 1, iy + 1};
  float wt4[4] = {(1.f - wy) * (1.f - wx), (1.f - wy) * wx, wy * (1.f - wx), wy * wx};
#pragma unroll
  for (int t = 0; t < 4; ++t) {
    if (wt4[t] != 0.f && (unsigned)yi[t] < 128u && (unsigned)xi[t] < 128u) {
      const u16* pp = gbase + (yi[t] << 7) + xi[t];
      float wv = wt4[t];
#pragma unroll
      for (int ch = 0; ch < 16; ++ch) acc[ch] = fmaf(wv, bfu(pp[(long)ch << 14]), acc[ch]);
    }
  }
#pragma unroll
  for (int ch = 0; ch < 16; ++ch) xds[p * 132 + (gg << 4) + ch] = acc[ch];
  __syncthreads();
  for (int i = 0; i < 16; ++i) {
    int lin = (i << 8) + tid;
    int cc = lin >> 5, pp2 = lin & 31;
    xs[(((long)(b << 7) + cc) << 14) + l0 + pp2] = fbf(xds[pp2 * 132 + cc]);
  }
  for (int task = tid; task < 320; task += 256) {
    int p2 = task / 10, r = task - p2 * 10;
    const float* wr = xpws + (r << 7);
    const float* xr = xds + p2 * 132;
    float sacc = 0.f;
#pragma unroll 8
    for (int cc = 0; cc < 128; ++cc) sacc = fmaf(wr[cc], xr[cc], sacc);
    xdbl[p2 * 12 + r] = sacc;
  }
  __syncthreads();
  for (int i = 0; i < 16; ++i) {
    int lin = (i << 8) + tid;
    int dd = lin >> 5, pp2 = lin & 31;
    const float* xb = xdbl + pp2 * 12;
    const float* wd = dtws + (dd << 3);
    float sacc = 0.f;
#pragma unroll
    for (int r = 0; r < 8; ++r) sacc = fmaf(wd[r], xb[r], sacc);
    dts[(((long)(b << 7) + dd) << 14) + l0 + pp2] = fbf(sacc);
  }
  if (tid < 32) {
    Bsb[((long)b << 14) + l0 + tid] = xdbl[tid * 12 + 8];
    Csb[((long)b << 14) + l0 + tid] = xdbl[tid * 12 + 9];
  }
}

// ---- K5: selective scan; xy holds xs on entry, y on exit (in-place) --------
__global__ __launch_bounds__(256) void k_scan(u16* __restrict__ xy,
                                              const u16* __restrict__ dts16,
                                              const float* __restrict__ Bsb,
                                              const float* __restrict__ Csb,
                                              const float* __restrict__ A_logs,
                                              const float* __restrict__ Dsv,
                                              const float* __restrict__ dtbv) {
  __shared__ float sp[256], se[256];
  int bd = blockIdx.x;
  int b = bd >> 7, d = bd & 127;
  float Ad = -__expf(A_logs[d]);
  float dtb = dtbv[d];
  float Dd = Dsv[d];
  int t = threadIdx.x;
  long base = ((long)bd << 14) + (t << 6);
  long bb = ((long)b << 14) + (t << 6);
  const ushort4* pz = (const ushort4*)(dts16 + base);
  const ushort4* px = (const ushort4*)(xy + base);
  const float4* pB = (const float4*)(Bsb + bb);
  const float4* pC = (const float4*)(Csb + bb);
  float h = 0.f, P = 1.f;
  for (int i = 0; i < 16; ++i) {
    ushort4 z4 = pz[i], x4 = px[i];
    float4 B4 = pB[i];
    float zz[4] = {bfu(z4.x), bfu(z4.y), bfu(z4.z), bfu(z4.w)};
    float xx[4] = {bfu(x4.x), bfu(x4.y), bfu(x4.z), bfu(x4.w)};
    float BB[4] = {B4.x, B4.y, B4.z, B4.w};
#pragma unroll
    for (int k = 0; k < 4; ++k) {
      float delta = softplusf(zz[k] + dtb);
      float a = __expf(delta * Ad);
      float u = delta * BB[k] * xx[k];
      h = fmaf(a, h, u);
      P *= a;
    }
  }
  sp[t] = P; se[t] = h;
  __syncthreads();
  for (int off = 1; off < 256; off <<= 1) {
    float pc = sp[t], ec = se[t];
    float pp = 1.f, ep = 0.f;
    bool actv = (t >= off);
    if (actv) { pp = sp[t - off]; ep = se[t - off]; }
    __syncthreads();
    if (actv) { sp[t] = pp * pc; se[t] = fmaf(pc, ep, ec); }
    __syncthreads();
  }
  h = (t == 0) ? 0.f : se[t - 1];
  ushort4* py = (ushort4*)(xy + base);
  for (int i = 0; i < 16; ++i) {
    ushort4 z4 = pz[i], x4 = px[i];
    float4 B4 = pB[i], C4 = pC[i];
    float zz[4] = {bfu(z4.x), bfu(z4.y), bfu(z4.z), bfu(z4.w)};
    float xx[4] = {bfu(x4.x), bfu(x4.y), bfu(x4.z), bfu(x4.w)};
    float BB[4] = {B4.x, B4.y, B4.z, B4.w};
    float CC[4] = {C4.x, C4.y, C4.z, C4.w};
    ushort4 sv;
    float yy[4];
#pragma unroll
    for (int k = 0; k < 4; ++k) {
      float delta = softplusf(zz[k] + dtb);
      float a = __expf(delta * Ad);
      float u = delta * BB[k] * xx[k];
      h = fmaf(a, h, u);
      yy[k] = fmaf(Dd, xx[k], h * CC[k]);
    }
    sv.x = fbf(yy[0]); sv.y = fbf(yy[1]); sv.z = fbf(yy[2]); sv.w = fbf(yy[3]);
    py[i] = sv;
  }
}

// ---- K6a: per-pixel mean/rstd of y over channels ---------------------------
__global__ __launch_bounds__(256) void k_stats(const u16* __restrict__ y,
                                               float* __restrict__ meanb,
                                               float* __restrict__ rstdb) {
  int pg = (blockIdx.x << 8) + threadIdx.x;
  int b = pg >> 14, l = pg & 16383;
  const u16* py = y + ((long)b << 21) + l;
  float s = 0.f, ss = 0.f;
  for (int c = 0; c < 128; ++c) { float v = bfu(py[(long)c << 14]); s += v; ss = fmaf(v, v, ss); }
  float m = s * (1.f / 128.f);
  meanb[pg] = m;
  rstdb[pg] = rsqrtf(ss * (1.f / 128.f) - m * m + 1e-6f);
}

// ---- K6b: s1[o]=sum W2*beta, s2[o]=sum W2*gamma ----------------------------
__global__ void k_sums(const float* __restrict__ W2, const float* __restrict__ g,
                       const float* __restrict__ bln, float* __restrict__ s12) {
  int o = threadIdx.x;
  float s1 = 0.f, s2 = 0.f;
  for (int c = 0; c < 128; ++c) {
    float w = W2[(o << 7) + c];
    s1 = fmaf(w, bln[c], s1);
    s2 = fmaf(w, g[c], s2);
  }
  s12[o] = s1;
  s12[128 + o] = s2;
}

// ---- K7: out_proj GEMM with LayerNorm folded into epilogue (f32 out) -------
__global__ __launch_bounds__(256) void k_outproj(const u16* __restrict__ y,
                                                 const float* __restrict__ W2,
                                                 const float* __restrict__ g,
                                                 const float* __restrict__ meanb,
                                                 const float* __restrict__ rstdb,
                                                 const float* __restrict__ s12,
                                                 float* __restrict__ out) {
  __shared__ __align__(16) u16 Wt[128 * 136];  // [c][o], bf16 of W2*gamma
  __shared__ __align__(16) u16 Ys[128 * 72];   // [c][p], bf16 y
  __shared__ float gs[128], s1s[128], s2s[128];
  int tid = threadIdx.x;
  if (tid < 128) { gs[tid] = g[tid]; s1s[tid] = s12[tid]; s2s[tid] = s12[128 + tid]; }
  __syncthreads();
  int b = blockIdx.x >> 8;
  int l0 = (blockIdx.x & 255) << 6;
  for (int i = 0; i < 64; ++i) {
    int lin = (i << 8) + tid;
    int o = lin >> 7, c = lin & 127;
    Wt[c * 136 + o] = fbf(W2[lin] * gs[c]);
  }
  for (int i = 0; i < 32; ++i) {
    int lin = (i << 8) + tid;
    int c = lin >> 6, p = lin & 63;
    Ys[c * 72 + p] = y[(((b << 7) + c) << 14) + l0 + p];
  }
  __syncthreads();
  int tx = tid & 15, ty = tid >> 4;
  int o0 = tx << 3, p0 = ty << 2;
  float acc[8][4] = {};
  for (int c = 0; c < 128; ++c) {
    uint4 aw = *(const uint4*)&Wt[c * 136 + o0];
    uint2 bw = *(const uint2*)&Ys[c * 72 + p0];
    float a[8], bv[4];
    a[0] = __uint_as_float(aw.x << 16); a[1] = __uint_as_float(aw.x & 0xffff0000u);
    a[2] = __uint_as_float(aw.y << 16); a[3] = __uint_as_float(aw.y & 0xffff0000u);
    a[4] = __uint_as_float(aw.z << 16); a[5] = __uint_as_float(aw.z & 0xffff0000u);
    a[6] = __uint_as_float(aw.w << 16); a[7] = __uint_as_float(aw.w & 0xffff0000u);
    bv[0] = __uint_as_float(bw.x << 16); bv[1] = __uint_as_float(bw.x & 0xffff0000u);
    bv[2] = __uint_as_float(bw.y << 16); bv[3] = __uint_as_float(bw.y & 0xffff0000u);
#pragma unroll
    for (int i = 0; i < 8; ++i)
#pragma unroll
      for (int j = 0; j < 4; ++j) acc[i][j] = fmaf(a[i], bv[j], acc[i][j]);
  }
  float4 m4 = *(const float4*)&meanb[((long)b << 14) + l0 + p0];
  float4 r4 = *(const float4*)&rstdb[((long)b << 14) + l0 + p0];
  float mm[4] = {m4.x, m4.y, m4.z, m4.w};
  float rr[4] = {r4.x, r4.y, r4.z, r4.w};
#pragma unroll
  for (int i = 0; i < 8; ++i) {
    int o = o0 + i;
    float s1v = s1s[o], s2v = s2s[o];
    float4 sv;
    sv.x = fmaf(rr[0], acc[i][0] - mm[0] * s2v, s1v);
    sv.y = fmaf(rr[1], acc[i][1] - mm[1] * s2v, s1v);
    sv.z = fmaf(rr[2], acc[i][2] - mm[2] * s2v, s1v);
    sv.w = fmaf(rr[3], acc[i][3] - mm[3] * s2v, s1v);
    *(float4*)&out[(((long)(b << 7) + o) << 14) + l0 + p0] = sv;
  }
}

extern "C" void kernel_launch(void* const* d_in, const int* in_sizes, int n_in,
                              void* d_out, int out_size, void* d_ws, size_t ws_size,
                              hipStream_t stream) {
  const float* x         = (const float*)d_in[0];
  const float* in_proj_w = (const float*)d_in[1];
  const float* conv2d_w  = (const float*)d_in[2];
  const float* conv2d_b  = (const float*)d_in[3];
  const float* dw_w      = (const float*)d_in[4];
  const float* dw_b      = (const float*)d_in[5];
  const float* dw_ln_g   = (const float*)d_in[6];
  const float* dw_ln_b   = (const float*)d_in[7];
  const float* off_w     = (const float*)d_in[8];
  const float* off_b     = (const float*)d_in[9];
  const float* x_proj_w  = (const float*)d_in[10];
  const float* dt_w      = (const float*)d_in[11];
  const float* dt_b      = (const float*)d_in[12];
  const float* A_logs    = (const float*)d_in[13];
  const float* Ds        = (const float*)d_in[14];
  const float* out_ln_g  = (const float*)d_in[15];
  const float* out_ln_b  = (const float*)d_in[16];
  const float* out_proj_w= (const float*)d_in[17];
  float* out = (float*)d_out;

  // bf16 internal buffers (u16), 8388608 elems each = 16 MiB
  u16* A  = (u16*)d_ws;            // xin -> x1 -> xs -> y (in-place)
  u16* Bx = A + 8388608;           // xc
  u16* Dd = Bx + 8388608;          // dts
  float* offs  = (float*)(Dd + 8388608);  // (B,L,16)
  float* Bsb   = offs + 1048576;
  float* Csb   = Bsb + 65536;
  float* meanb = Csb + 65536;
  float* rstdb = meanb + 65536;
  float* s12   = rstdb + 65536;

  hipLaunchKernelGGL(k_inproj, dim3(1024), dim3(256), 0, stream, x, in_proj_w, A);
  hipLaunchKernelGGL(k_dwconv, dim3(32768), dim3(256), 0, stream, A, conv2d_w, conv2d_b, Bx, 1);
  hipLaunchKernelGGL(k_dwconv, dim3(32768), dim3(256), 0, stream, Bx, dw_w, dw_b, A, 0);
  hipLaunchKernelGGL(k_offset, dim3(256), dim3(256), 0, stream, A, dw_ln_g, dw_ln_b, off_w, off_b, offs);
  hipLaunchKernelGGL(k_dcn, dim3(2048), dim3(256), 0, stream, Bx, offs, x_proj_w, dt_w, A, Dd, Bsb, Csb);
  hipLaunchKernelGGL(k_scan, dim3(512), dim3(256), 0, stream, A, Dd, Bsb, Csb, A_logs, Ds, dt_b);
  hipLaunchKernelGGL(k_stats, dim3(256), dim3(256), 0, stream, A, meanb, rstdb);
  hipLaunchKernelGGL(k_sums, dim3(1), dim3(128), 0, stream, out_proj_w, out_ln_g, out_ln_b, s12);
  hipLaunchKernelGGL(k_outproj, dim3(1024), dim3(256), 0, stream, A, out_proj_w, out_ln_g, meanb, rstdb, s12, out);
}

// Round 3
// 422.131 us; speedup vs baseline: 1.0827x; 1.0827x over previous
//
#include <hip/hip_runtime.h>
#include <hip/hip_bf16.h>

typedef unsigned short u16;
typedef unsigned int u32;

__device__ __forceinline__ float bfu(u16 u) { return __uint_as_float(((u32)u) << 16); }
__device__ __forceinline__ u16 fbf(float f) {
  __hip_bfloat16 h = __float2bfloat16(f);
  return *reinterpret_cast<u16*>(&h);
}
__device__ __forceinline__ float softplusf(float z) {
  return (z > 20.f) ? z : log1pf(__expf(z));
}
__device__ __forceinline__ float lo16(u32 p) { return __uint_as_float(p << 16); }
__device__ __forceinline__ float hi16(u32 p) { return __uint_as_float(p & 0xffff0000u); }

// ---- K1: in_proj GEMM: out[b,o,l] = sum_c W[o,c] * x[b,c,l]  (f32 in, bf16 out)
__global__ __launch_bounds__(256) void k_inproj(const float* __restrict__ X,
                                                const float* __restrict__ W,
                                                u16* __restrict__ out) {
  __shared__ __align__(16) u16 Wt[128 * 136];  // [c][o]
  __shared__ __align__(16) u16 Xs[128 * 72];   // [c][p]
  int tid = threadIdx.x;
  int b = blockIdx.x >> 8;
  int l0 = (blockIdx.x & 255) << 6;
  for (int i = 0; i < 64; ++i) {
    int lin = (i << 8) + tid;
    int o = lin >> 7, c = lin & 127;
    Wt[c * 136 + o] = fbf(W[lin]);
  }
  for (int i = 0; i < 32; ++i) {
    int lin = (i << 8) + tid;
    int c = lin >> 6, p = lin & 63;
    Xs[c * 72 + p] = fbf(X[(((b << 7) + c) << 14) + l0 + p]);
  }
  __syncthreads();
  int tx = tid & 15, ty = tid >> 4;
  int o0 = tx << 3, p0 = ty << 2;
  float acc[8][4] = {};
  for (int c = 0; c < 128; ++c) {
    uint4 aw = *(const uint4*)&Wt[c * 136 + o0];
    uint2 bw = *(const uint2*)&Xs[c * 72 + p0];
    float a[8], bv[4];
    a[0] = lo16(aw.x); a[1] = hi16(aw.x);
    a[2] = lo16(aw.y); a[3] = hi16(aw.y);
    a[4] = lo16(aw.z); a[5] = hi16(aw.z);
    a[6] = lo16(aw.w); a[7] = hi16(aw.w);
    bv[0] = lo16(bw.x); bv[1] = hi16(bw.x);
    bv[2] = lo16(bw.y); bv[3] = hi16(bw.y);
#pragma unroll
    for (int i = 0; i < 8; ++i)
#pragma unroll
      for (int j = 0; j < 4; ++j) acc[i][j] = fmaf(a[i], bv[j], acc[i][j]);
  }
#pragma unroll
  for (int i = 0; i < 8; ++i) {
    ushort4 sv;
    sv.x = fbf(acc[i][0]); sv.y = fbf(acc[i][1]);
    sv.z = fbf(acc[i][2]); sv.w = fbf(acc[i][3]);
    *(ushort4*)&out[(((b << 7) + o0 + i) << 14) + l0 + p0] = sv;
  }
}

// ---- K2/K3a: depthwise 3x3 conv (bf16 in/out, f32 weights), optional SiLU --
__global__ __launch_bounds__(256) void k_dwconv(const u16* __restrict__ in,
                                                const float* __restrict__ w9,
                                                const float* __restrict__ bias,
                                                u16* __restrict__ out, int act) {
  int blk = blockIdx.x;
  int bc = blk >> 6;
  int c = bc & 127;
  int h = ((blk & 63) << 1) + (threadIdx.x >> 7);
  int w = threadIdx.x & 127;
  float wt[9];
#pragma unroll
  for (int k = 0; k < 9; ++k) wt[k] = w9[c * 9 + k];
  const u16* base = in + ((long)bc << 14);
  float acc = bias[c];
#pragma unroll
  for (int ky = -1; ky <= 1; ++ky) {
    int y = h + ky;
    if ((unsigned)y < 128u) {
      const u16* row = base + (y << 7);
#pragma unroll
      for (int kx = -1; kx <= 1; ++kx) {
        int x = w + kx;
        if ((unsigned)x < 128u) acc = fmaf(wt[(ky + 1) * 3 + kx + 1], bfu(row[x]), acc);
      }
    }
  }
  if (act) acc = acc / (1.f + __expf(-acc));
  out[((long)bc << 14) + (h << 7) + w] = fbf(acc);
}

// ---- K3b: per-pixel LN(channels) + GELU + offset projection (16 outputs) ---
__global__ __launch_bounds__(256) void k_offset(const u16* __restrict__ x1,
                                                const float* __restrict__ g,
                                                const float* __restrict__ bt,
                                                const float* __restrict__ offw,
                                                const float* __restrict__ offb,
                                                float* __restrict__ offs) {
  __shared__ float Wo[16 * 128];
  __shared__ float gs[128], bs[128];
  int tid = threadIdx.x;
  if (tid < 128) { gs[tid] = g[tid]; bs[tid] = bt[tid]; }
  for (int i = 0; i < 8; ++i) { int idx = (i << 8) + tid; Wo[idx] = offw[idx]; }
  __syncthreads();
  int pg = (blockIdx.x << 8) + tid;
  int b = pg >> 14, l = pg & 16383;
  const u16* px = x1 + ((long)b << 21) + l;
  float s = 0.f, ss = 0.f;
  for (int c = 0; c < 128; ++c) { float v = bfu(px[(long)c << 14]); s += v; ss = fmaf(v, v, ss); }
  float mean = s * (1.f / 128.f);
  float var = ss * (1.f / 128.f) - mean * mean;
  float rstd = rsqrtf(var + 1e-6f);
  float acc[16];
#pragma unroll
  for (int j = 0; j < 16; ++j) acc[j] = offb[j];
  for (int c = 0; c < 128; ++c) {
    float v = bfu(px[(long)c << 14]);
    float xn = fmaf((v - mean) * rstd, gs[c], bs[c]);
    float ge = 0.5f * xn * (1.f + erff(xn * 0.70710678118f));
#pragma unroll
    for (int j = 0; j < 16; ++j) acc[j] = fmaf(Wo[j * 128 + c], ge, acc[j]);
  }
  float* po = offs + ((long)pg << 4);
#pragma unroll
  for (int j = 0; j < 4; ++j)
    *(float4*)&po[j << 2] = make_float4(acc[4 * j], acc[4 * j + 1], acc[4 * j + 2], acc[4 * j + 3]);
}

// ---- K4: DCN bilinear gather + x_proj (10x128) + dt_w (128x8) fused --------
__global__ __launch_bounds__(256) void k_dcn(const u16* __restrict__ xc,
                                             const float* __restrict__ offs,
                                             const float* __restrict__ xpw,
                                             const float* __restrict__ dtw,
                                             u16* __restrict__ xs,
                                             u16* __restrict__ dts,
                                             float* __restrict__ Bsb,
                                             float* __restrict__ Csb) {
  __shared__ float xds[32 * 132];
  __shared__ float xdbl[32 * 12];
  __shared__ float xpws[1280];
  __shared__ float dtws[1024];
  int tid = threadIdx.x;
  for (int i = 0; i < 5; ++i) { int idx = (i << 8) + tid; if (idx < 1280) xpws[idx] = xpw[idx]; }
  for (int i = 0; i < 4; ++i) { int idx = (i << 8) + tid; dtws[idx] = dtw[idx]; }
  int blk = blockIdx.x;
  int b = blk >> 9;
  int l0 = (blk & 511) << 5;
  int p = tid >> 3, gg = tid & 7;
  int l = l0 + p, hh = l >> 7, ww = l & 127;
  float2 off = *(const float2*)&offs[(((long)(b << 14) + l) << 4) + (gg << 1)];
  float px = (float)ww + off.x, py = (float)hh + off.y;
  float x0f = floorf(px), y0f = floorf(py);
  float wx = px - x0f, wy = py - y0f;
  int ix = (int)x0f, iy = (int)y0f;
  float acc[16];
#pragma unroll
  for (int ch = 0; ch < 16; ++ch) acc[ch] = 0.f;
  const u16* gbase = xc + (((long)(b << 7) + (gg << 4)) << 14);
  int xi[4] = {ix, ix + 1, ix, ix + 1};
  int yi[4] = {iy, iy, iy + 1, iy + 1};
  float wt4[4] = {(1.f - wy) * (1.f - wx), (1.f - wy) * wx, wy * (1.f - wx), wy * wx};
#pragma unroll
  for (int t = 0; t < 4; ++t) {
    if (wt4[t] != 0.f && (unsigned)yi[t] < 128u && (unsigned)xi[t] < 128u) {
      const u16* pp = gbase + (yi[t] << 7) + xi[t];
      float wv = wt4[t];
#pragma unroll
      for (int ch = 0; ch < 16; ++ch) acc[ch] = fmaf(wv, bfu(pp[(long)ch << 14]), acc[ch]);
    }
  }
#pragma unroll
  for (int ch = 0; ch < 16; ++ch) xds[p * 132 + (gg << 4) + ch] = acc[ch];
  __syncthreads();
  for (int i = 0; i < 16; ++i) {
    int lin = (i << 8) + tid;
    int cc = lin >> 5, pp2 = lin & 31;
    xs[(((long)(b << 7) + cc) << 14) + l0 + pp2] = fbf(xds[pp2 * 132 + cc]);
  }
  for (int task = tid; task < 320; task += 256) {
    int p2 = task / 10, r = task - p2 * 10;
    const float* wr = xpws + (r << 7);
    const float* xr = xds + p2 * 132;
    float sacc = 0.f;
#pragma unroll 8
    for (int cc = 0; cc < 128; ++cc) sacc = fmaf(wr[cc], xr[cc], sacc);
    xdbl[p2 * 12 + r] = sacc;
  }
  __syncthreads();
  for (int i = 0; i < 16; ++i) {
    int lin = (i << 8) + tid;
    int dd = lin >> 5, pp2 = lin & 31;
    const float* xb = xdbl + pp2 * 12;
    const float* wd = dtws + (dd << 3);
    float sacc = 0.f;
#pragma unroll
    for (int r = 0; r < 8; ++r) sacc = fmaf(wd[r], xb[r], sacc);
    dts[(((long)(b << 7) + dd) << 14) + l0 + pp2] = fbf(sacc);
  }
  if (tid < 32) {
    Bsb[((long)b << 14) + l0 + tid] = xdbl[tid * 12 + 8];
    Csb[((long)b << 14) + l0 + tid] = xdbl[tid * 12 + 9];
  }
}

// ---- K5: selective scan, single global pass, register-cached coefficients --
// xy holds xs on entry, y on exit (in-place). 512 thr x 32 elem = L=16384.
__global__ __launch_bounds__(512, 4) void k_scan(u16* __restrict__ xy,
                                                 const u16* __restrict__ dts16,
                                                 const float* __restrict__ Bsb,
                                                 const float* __restrict__ Csb,
                                                 const float* __restrict__ A_logs,
                                                 const float* __restrict__ Dsv,
                                                 const float* __restrict__ dtbv) {
  __shared__ float sp[512], se[512];
  int bd = blockIdx.x;
  int b = bd >> 7, d = bd & 127;
  float Ad = -__expf(A_logs[d]);
  float dtb = dtbv[d];
  float Dd = Dsv[d];
  int t = threadIdx.x;
  long base = ((long)bd << 14) + (t << 5);
  long bb = ((long)b << 14) + (t << 5);
  const uint4* pz4 = (const uint4*)(dts16 + base);  // 32 bf16 = 4 x 16B
  const uint4* px4 = (const uint4*)(xy + base);
  const float4* pB = (const float4*)(Bsb + bb);     // 32 f32 = 8 x 16B
  const float4* pC = (const float4*)(Csb + bb);

  float a[32];          // decay per element (f32 — precision-critical)
  u32 upk[16], cpk[16], dpk[16];  // u, C, D*x packed bf16 pairs
  float h = 0.f, P = 1.f;

#pragma unroll
  for (int ck = 0; ck < 4; ++ck) {   // 4 chunks of 8 elements
    uint4 z4 = pz4[ck];
    uint4 x4 = px4[ck];
    float4 B0 = pB[2 * ck], B1 = pB[2 * ck + 1];
    float4 C0 = pC[2 * ck], C1 = pC[2 * ck + 1];
    u32 zw[4] = {z4.x, z4.y, z4.z, z4.w};
    u32 xw[4] = {x4.x, x4.y, x4.z, x4.w};
    float Bf[8] = {B0.x, B0.y, B0.z, B0.w, B1.x, B1.y, B1.z, B1.w};
    float Cf[8] = {C0.x, C0.y, C0.z, C0.w, C1.x, C1.y, C1.z, C1.w};
#pragma unroll
    for (int j = 0; j < 8; ++j) {
      int k = (ck << 3) + j;
      float z = (j & 1) ? hi16(zw[j >> 1]) : lo16(zw[j >> 1]);
      float xv = (j & 1) ? hi16(xw[j >> 1]) : lo16(xw[j >> 1]);
      float delta = softplusf(z + dtb);
      float av = __expf(delta * Ad);
      float uv = delta * Bf[j] * xv;
      a[k] = av;
      u16 ub = fbf(uv), cb = fbf(Cf[j]), db = fbf(Dd * xv);
      if ((k & 1) == 0) {
        upk[k >> 1] = ub; cpk[k >> 1] = cb; dpk[k >> 1] = db;
      } else {
        upk[k >> 1] |= (u32)ub << 16; cpk[k >> 1] |= (u32)cb << 16; dpk[k >> 1] |= (u32)db << 16;
      }
      h = fmaf(av, h, uv);
      P *= av;
    }
  }
  sp[t] = P; se[t] = h;
  __syncthreads();
  for (int off = 1; off < 512; off <<= 1) {
    float pc = sp[t], ec = se[t];
    float pp = 1.f, ep = 0.f;
    bool actv = (t >= off);
    if (actv) { pp = sp[t - off]; ep = se[t - off]; }
    __syncthreads();
    if (actv) { sp[t] = pp * pc; se[t] = fmaf(pc, ep, ec); }
    __syncthreads();
  }
  h = (t == 0) ? 0.f : se[t - 1];
  u32 ypk[16];
#pragma unroll
  for (int k = 0; k < 32; ++k) {
    float uv = (k & 1) ? hi16(upk[k >> 1]) : lo16(upk[k >> 1]);
    float cv = (k & 1) ? hi16(cpk[k >> 1]) : lo16(cpk[k >> 1]);
    float dv = (k & 1) ? hi16(dpk[k >> 1]) : lo16(dpk[k >> 1]);
    h = fmaf(a[k], h, uv);
    u16 yb = fbf(fmaf(h, cv, dv));
    if ((k & 1) == 0) ypk[k >> 1] = yb; else ypk[k >> 1] |= (u32)yb << 16;
  }
  uint4* py = (uint4*)(xy + base);
#pragma unroll
  for (int i = 0; i < 4; ++i)
    py[i] = make_uint4(ypk[4 * i], ypk[4 * i + 1], ypk[4 * i + 2], ypk[4 * i + 3]);
}

// ---- K6a: per-pixel mean/rstd of y over channels ---------------------------
__global__ __launch_bounds__(256) void k_stats(const u16* __restrict__ y,
                                               float* __restrict__ meanb,
                                               float* __restrict__ rstdb) {
  int pg = (blockIdx.x << 8) + threadIdx.x;
  int b = pg >> 14, l = pg & 16383;
  const u16* py = y + ((long)b << 21) + l;
  float s = 0.f, ss = 0.f;
  for (int c = 0; c < 128; ++c) { float v = bfu(py[(long)c << 14]); s += v; ss = fmaf(v, v, ss); }
  float m = s * (1.f / 128.f);
  meanb[pg] = m;
  rstdb[pg] = rsqrtf(ss * (1.f / 128.f) - m * m + 1e-6f);
}

// ---- K6b: s1[o]=sum W2*beta, s2[o]=sum W2*gamma ----------------------------
__global__ void k_sums(const float* __restrict__ W2, const float* __restrict__ g,
                       const float* __restrict__ bln, float* __restrict__ s12) {
  int o = threadIdx.x;
  float s1 = 0.f, s2 = 0.f;
  for (int c = 0; c < 128; ++c) {
    float w = W2[(o << 7) + c];
    s1 = fmaf(w, bln[c], s1);
    s2 = fmaf(w, g[c], s2);
  }
  s12[o] = s1;
  s12[128 + o] = s2;
}

// ---- K7: out_proj GEMM with LayerNorm folded into epilogue (f32 out) -------
__global__ __launch_bounds__(256) void k_outproj(const u16* __restrict__ y,
                                                 const float* __restrict__ W2,
                                                 const float* __restrict__ g,
                                                 const float* __restrict__ meanb,
                                                 const float* __restrict__ rstdb,
                                                 const float* __restrict__ s12,
                                                 float* __restrict__ out) {
  __shared__ __align__(16) u16 Wt[128 * 136];  // [c][o], bf16 of W2*gamma
  __shared__ __align__(16) u16 Ys[128 * 72];   // [c][p], bf16 y
  __shared__ float gs[128], s1s[128], s2s[128];
  int tid = threadIdx.x;
  if (tid < 128) { gs[tid] = g[tid]; s1s[tid] = s12[tid]; s2s[tid] = s12[128 + tid]; }
  __syncthreads();
  int b = blockIdx.x >> 8;
  int l0 = (blockIdx.x & 255) << 6;
  for (int i = 0; i < 64; ++i) {
    int lin = (i << 8) + tid;
    int o = lin >> 7, c = lin & 127;
    Wt[c * 136 + o] = fbf(W2[lin] * gs[c]);
  }
  for (int i = 0; i < 32; ++i) {
    int lin = (i << 8) + tid;
    int c = lin >> 6, p = lin & 63;
    Ys[c * 72 + p] = y[(((b << 7) + c) << 14) + l0 + p];
  }
  __syncthreads();
  int tx = tid & 15, ty = tid >> 4;
  int o0 = tx << 3, p0 = ty << 2;
  float acc[8][4] = {};
  for (int c = 0; c < 128; ++c) {
    uint4 aw = *(const uint4*)&Wt[c * 136 + o0];
    uint2 bw = *(const uint2*)&Ys[c * 72 + p0];
    float a[8], bv[4];
    a[0] = lo16(aw.x); a[1] = hi16(aw.x);
    a[2] = lo16(aw.y); a[3] = hi16(aw.y);
    a[4] = lo16(aw.z); a[5] = hi16(aw.z);
    a[6] = lo16(aw.w); a[7] = hi16(aw.w);
    bv[0] = lo16(bw.x); bv[1] = hi16(bw.x);
    bv[2] = lo16(bw.y); bv[3] = hi16(bw.y);
#pragma unroll
    for (int i = 0; i < 8; ++i)
#pragma unroll
      for (int j = 0; j < 4; ++j) acc[i][j] = fmaf(a[i], bv[j], acc[i][j]);
  }
  float4 m4 = *(const float4*)&meanb[((long)b << 14) + l0 + p0];
  float4 r4 = *(const float4*)&rstdb[((long)b << 14) + l0 + p0];
  float mm[4] = {m4.x, m4.y, m4.z, m4.w};
  float rr[4] = {r4.x, r4.y, r4.z, r4.w};
#pragma unroll
  for (int i = 0; i < 8; ++i) {
    int o = o0 + i;
    float s1v = s1s[o], s2v = s2s[o];
    float4 sv;
    sv.x = fmaf(rr[0], acc[i][0] - mm[0] * s2v, s1v);
    sv.y = fmaf(rr[1], acc[i][1] - mm[1] * s2v, s1v);
    sv.z = fmaf(rr[2], acc[i][2] - mm[2] * s2v, s1v);
    sv.w = fmaf(rr[3], acc[i][3] - mm[3] * s2v, s1v);
    *(float4*)&out[(((long)(b << 7) + o) << 14) + l0 + p0] = sv;
  }
}

extern "C" void kernel_launch(void* const* d_in, const int* in_sizes, int n_in,
                              void* d_out, int out_size, void* d_ws, size_t ws_size,
                              hipStream_t stream) {
  const float* x         = (const float*)d_in[0];
  const float* in_proj_w = (const float*)d_in[1];
  const float* conv2d_w  = (const float*)d_in[2];
  const float* conv2d_b  = (const float*)d_in[3];
  const float* dw_w      = (const float*)d_in[4];
  const float* dw_b      = (const float*)d_in[5];
  const float* dw_ln_g   = (const float*)d_in[6];
  const float* dw_ln_b   = (const float*)d_in[7];
  const float* off_w     = (const float*)d_in[8];
  const float* off_b     = (const float*)d_in[9];
  const float* x_proj_w  = (const float*)d_in[10];
  const float* dt_w      = (const float*)d_in[11];
  const float* dt_b      = (const float*)d_in[12];
  const float* A_logs    = (const float*)d_in[13];
  const float* Ds        = (const float*)d_in[14];
  const float* out_ln_g  = (const float*)d_in[15];
  const float* out_ln_b  = (const float*)d_in[16];
  const float* out_proj_w= (const float*)d_in[17];
  float* out = (float*)d_out;

  // bf16 internal buffers (u16), 8388608 elems each = 16 MiB
  u16* A  = (u16*)d_ws;            // xin -> x1 -> xs -> y (in-place)
  u16* Bx = A + 8388608;           // xc
  u16* Dd = Bx + 8388608;          // dts
  float* offs  = (float*)(Dd + 8388608);  // (B,L,16)
  float* Bsb   = offs + 1048576;
  float* Csb   = Bsb + 65536;
  float* meanb = Csb + 65536;
  float* rstdb = meanb + 65536;
  float* s12   = rstdb + 65536;

  hipLaunchKernelGGL(k_inproj, dim3(1024), dim3(256), 0, stream, x, in_proj_w, A);
  hipLaunchKernelGGL(k_dwconv, dim3(32768), dim3(256), 0, stream, A, conv2d_w, conv2d_b, Bx, 1);
  hipLaunchKernelGGL(k_dwconv, dim3(32768), dim3(256), 0, stream, Bx, dw_w, dw_b, A, 0);
  hipLaunchKernelGGL(k_offset, dim3(256), dim3(256), 0, stream, A, dw_ln_g, dw_ln_b, off_w, off_b, offs);
  hipLaunchKernelGGL(k_dcn, dim3(2048), dim3(256), 0, stream, Bx, offs, x_proj_w, dt_w, A, Dd, Bsb, Csb);
  hipLaunchKernelGGL(k_scan, dim3(512), dim3(512), 0, stream, A, Dd, Bsb, Csb, A_logs, Ds, dt_b);
  hipLaunchKernelGGL(k_stats, dim3(256), dim3(256), 0, stream, A, meanb, rstdb);
  hipLaunchKernelGGL(k_sums, dim3(1), dim3(128), 0, stream, out_proj_w, out_ln_g, out_ln_b, s12);
  hipLaunchKernelGGL(k_outproj, dim3(1024), dim3(256), 0, stream, A, out_proj_w, out_ln_g, meanb, rstdb, s12, out);
}

// Round 4
// 359.224 us; speedup vs baseline: 1.2723x; 1.1751x over previous
//
#include <hip/hip_runtime.h>
#include <hip/hip_bf16.h>

typedef unsigned short u16;
typedef unsigned int u32;

__device__ __forceinline__ float bfu(u16 u) { return __uint_as_float(((u32)u) << 16); }
__device__ __forceinline__ u16 fbf(float f) {
  __hip_bfloat16 h = __float2bfloat16(f);
  return *reinterpret_cast<u16*>(&h);
}
__device__ __forceinline__ float softplusf(float z) {
  return (z > 20.f) ? z : log1pf(__expf(z));
}
__device__ __forceinline__ float lo16(u32 p) { return __uint_as_float(p << 16); }
__device__ __forceinline__ float hi16(u32 p) { return __uint_as_float(p & 0xffff0000u); }

// ---- K1: in_proj GEMM: out_cl[b,l,o] = sum_c W[o,c] * x[b,c,l] ------------
__global__ __launch_bounds__(256) void k_inproj(const float* __restrict__ X,
                                                const float* __restrict__ W,
                                                u16* __restrict__ out) {
  __shared__ __align__(16) u16 Wt[128 * 136];  // [c][o]
  __shared__ __align__(16) u16 Xs[128 * 72];   // [c][p]
  int tid = threadIdx.x;
  int b = blockIdx.x >> 8;
  int l0 = (blockIdx.x & 255) << 6;
  for (int i = 0; i < 64; ++i) {
    int lin = (i << 8) + tid;
    int o = lin >> 7, c = lin & 127;
    Wt[c * 136 + o] = fbf(W[lin]);
  }
  for (int i = 0; i < 32; ++i) {
    int lin = (i << 8) + tid;
    int c = lin >> 6, p = lin & 63;
    Xs[c * 72 + p] = fbf(X[(((b << 7) + c) << 14) + l0 + p]);
  }
  __syncthreads();
  int tx = tid & 15, ty = tid >> 4;
  int o0 = tx << 3, p0 = ty << 2;
  float acc[8][4] = {};
  for (int c = 0; c < 128; ++c) {
    uint4 aw = *(const uint4*)&Wt[c * 136 + o0];
    uint2 bw = *(const uint2*)&Xs[c * 72 + p0];
    float a[8], bv[4];
    a[0] = lo16(aw.x); a[1] = hi16(aw.x);
    a[2] = lo16(aw.y); a[3] = hi16(aw.y);
    a[4] = lo16(aw.z); a[5] = hi16(aw.z);
    a[6] = lo16(aw.w); a[7] = hi16(aw.w);
    bv[0] = lo16(bw.x); bv[1] = hi16(bw.x);
    bv[2] = lo16(bw.y); bv[3] = hi16(bw.y);
#pragma unroll
    for (int i = 0; i < 8; ++i)
#pragma unroll
      for (int j = 0; j < 4; ++j) acc[i][j] = fmaf(a[i], bv[j], acc[i][j]);
  }
  // channels-last store: 8 consecutive o per thread per l
#pragma unroll
  for (int j = 0; j < 4; ++j) {
    int l = l0 + p0 + j;
    ushort4 s0, s1;
    s0.x = fbf(acc[0][j]); s0.y = fbf(acc[1][j]);
    s0.z = fbf(acc[2][j]); s0.w = fbf(acc[3][j]);
    s1.x = fbf(acc[4][j]); s1.y = fbf(acc[5][j]);
    s1.z = fbf(acc[6][j]); s1.w = fbf(acc[7][j]);
    u16* po = out + ((((long)(b << 14) + l)) << 7) + o0;
    *(ushort4*)po = s0;
    *(ushort4*)(po + 4) = s1;
  }
}

// ---- K2/K3a: depthwise 3x3 conv, channels-last, optional SiLU --------------
// block = 16 pixels (one row strip) x 16 channel-octets
__global__ __launch_bounds__(256) void k_dwconv(const u16* __restrict__ in,
                                                const float* __restrict__ w9,
                                                const float* __restrict__ bias,
                                                u16* __restrict__ out, int act) {
  __shared__ float wsT[9][128];
  __shared__ float bs[128];
  int tid = threadIdx.x;
  for (int i = 0; i < 5; ++i) {
    int lin = (i << 8) + tid;
    if (lin < 1152) { int c = lin / 9, k = lin - 9 * c; wsT[k][c] = w9[lin]; }
  }
  if (tid < 128) bs[tid] = bias[tid];
  __syncthreads();
  int blk = blockIdx.x;
  int b = blk >> 10;
  int s = blk & 1023;
  int h = s >> 3;
  int w = ((s & 7) << 4) + (tid >> 4);
  int c0 = (tid & 15) << 3;
  const u16* bbase = in + ((long)b << 21);
  float acc[8];
  {
    float4 b0 = *(const float4*)&bs[c0];
    float4 b1 = *(const float4*)&bs[c0 + 4];
    acc[0] = b0.x; acc[1] = b0.y; acc[2] = b0.z; acc[3] = b0.w;
    acc[4] = b1.x; acc[5] = b1.y; acc[6] = b1.z; acc[7] = b1.w;
  }
#pragma unroll
  for (int ky = -1; ky <= 1; ++ky) {
    int y = h + ky;
    if ((unsigned)y >= 128u) continue;
#pragma unroll
    for (int kx = -1; kx <= 1; ++kx) {
      int x = w + kx;
      if ((unsigned)x >= 128u) continue;
      int k = (ky + 1) * 3 + (kx + 1);
      uint4 v = *(const uint4*)(bbase + ((((y << 7) + x)) << 7) + c0);
      float4 w0 = *(const float4*)&wsT[k][c0];
      float4 w1 = *(const float4*)&wsT[k][c0 + 4];
      u32 vv[4] = {v.x, v.y, v.z, v.w};
      float wf[8] = {w0.x, w0.y, w0.z, w0.w, w1.x, w1.y, w1.z, w1.w};
#pragma unroll
      for (int cc = 0; cc < 8; ++cc) {
        float xv = (cc & 1) ? hi16(vv[cc >> 1]) : lo16(vv[cc >> 1]);
        acc[cc] = fmaf(wf[cc], xv, acc[cc]);
      }
    }
  }
  if (act) {
#pragma unroll
    for (int cc = 0; cc < 8; ++cc) acc[cc] = acc[cc] / (1.f + __expf(-acc[cc]));
  }
  ushort4 s0, s1;
  s0.x = fbf(acc[0]); s0.y = fbf(acc[1]); s0.z = fbf(acc[2]); s0.w = fbf(acc[3]);
  s1.x = fbf(acc[4]); s1.y = fbf(acc[5]); s1.z = fbf(acc[6]); s1.w = fbf(acc[7]);
  u16* po = out + ((long)b << 21) + ((((h << 7) + w)) << 7) + c0;
  *(ushort4*)po = s0;
  *(ushort4*)(po + 4) = s1;
}

// ---- K3b: per-pixel LN + GELU + offset projection, channels-last -----------
__global__ __launch_bounds__(256) void k_offset(const u16* __restrict__ x1,
                                                const float* __restrict__ g,
                                                const float* __restrict__ bt,
                                                const float* __restrict__ offw,
                                                const float* __restrict__ offb,
                                                float* __restrict__ offs) {
  __shared__ float Wo[16 * 128];
  __shared__ float gs[128], bsh[128];
  int tid = threadIdx.x;
  if (tid < 128) { gs[tid] = g[tid]; bsh[tid] = bt[tid]; }
  for (int i = 0; i < 8; ++i) { int idx = (i << 8) + tid; Wo[idx] = offw[idx]; }
  __syncthreads();
  int pg = (blockIdx.x << 8) + tid;  // b*L + l
  const uint4* px = (const uint4*)(x1 + ((long)pg << 7));
  float s = 0.f, ss = 0.f;
  for (int i = 0; i < 16; ++i) {
    uint4 v = px[i];
    u32 vv[4] = {v.x, v.y, v.z, v.w};
#pragma unroll
    for (int cc = 0; cc < 8; ++cc) {
      float xv = (cc & 1) ? hi16(vv[cc >> 1]) : lo16(vv[cc >> 1]);
      s += xv; ss = fmaf(xv, xv, ss);
    }
  }
  float mean = s * (1.f / 128.f);
  float var = ss * (1.f / 128.f) - mean * mean;
  float rstd = rsqrtf(var + 1e-6f);
  float acc[16];
#pragma unroll
  for (int j = 0; j < 16; ++j) acc[j] = offb[j];
  for (int i = 0; i < 16; ++i) {
    uint4 v = px[i];  // L1 hit
    u32 vv[4] = {v.x, v.y, v.z, v.w};
#pragma unroll
    for (int cc = 0; cc < 8; ++cc) {
      int c = (i << 3) + cc;
      float xv = (cc & 1) ? hi16(vv[cc >> 1]) : lo16(vv[cc >> 1]);
      float xn = fmaf((xv - mean) * rstd, gs[c], bsh[c]);
      float ge = 0.5f * xn * (1.f + erff(xn * 0.70710678118f));
#pragma unroll
      for (int j = 0; j < 16; ++j) acc[j] = fmaf(Wo[j * 128 + c], ge, acc[j]);
    }
  }
  float* po = offs + ((long)pg << 4);
#pragma unroll
  for (int j = 0; j < 4; ++j)
    *(float4*)&po[j << 2] = make_float4(acc[4 * j], acc[4 * j + 1], acc[4 * j + 2], acc[4 * j + 3]);
}

// ---- K4: DCN bilinear gather (channels-last) + x_proj + dt_w fused ---------
__global__ __launch_bounds__(256) void k_dcn(const u16* __restrict__ xc,
                                             const float* __restrict__ offs,
                                             const float* __restrict__ xpw,
                                             const float* __restrict__ dtw,
                                             u16* __restrict__ xs,
                                             u16* __restrict__ dts,
                                             float* __restrict__ Bsb,
                                             float* __restrict__ Csb) {
  __shared__ float xds[32 * 129];
  __shared__ float xdbl[32 * 12];
  __shared__ float xpws[1280];
  __shared__ float dtws[1024];
  int tid = threadIdx.x;
  for (int i = 0; i < 5; ++i) { int idx = (i << 8) + tid; if (idx < 1280) xpws[idx] = xpw[idx]; }
  for (int i = 0; i < 4; ++i) { int idx = (i << 8) + tid; dtws[idx] = dtw[idx]; }
  int blk = blockIdx.x;
  int b = blk >> 9;
  int l0 = (blk & 511) << 5;
  int p = tid >> 3, gg = tid & 7;
  int l = l0 + p, hh = l >> 7, ww = l & 127;
  float2 off = *(const float2*)&offs[(((long)(b << 14) + l) << 4) + (gg << 1)];
  float px = (float)ww + off.x, py = (float)hh + off.y;
  float x0f = floorf(px), y0f = floorf(py);
  float wx = px - x0f, wy = py - y0f;
  int ix = (int)x0f, iy = (int)y0f;
  float acc[16];
#pragma unroll
  for (int ch = 0; ch < 16; ++ch) acc[ch] = 0.f;
  const u16* bbase = xc + ((long)b << 21) + (gg << 4);
  int xi[4] = {ix, ix + 1, ix, ix + 1};
  int yi[4] = {iy, iy, iy + 1, iy + 1};
  float wt4[4] = {(1.f - wy) * (1.f - wx), (1.f - wy) * wx, wy * (1.f - wx), wy * wx};
#pragma unroll
  for (int t = 0; t < 4; ++t) {
    if (wt4[t] != 0.f && (unsigned)yi[t] < 128u && (unsigned)xi[t] < 128u) {
      const u16* pp = bbase + ((((yi[t] << 7) + xi[t])) << 7);
      uint4 v0 = *(const uint4*)pp;
      uint4 v1 = *(const uint4*)(pp + 8);
      float wv = wt4[t];
      u32 vv[8] = {v0.x, v0.y, v0.z, v0.w, v1.x, v1.y, v1.z, v1.w};
#pragma unroll
      for (int ch = 0; ch < 16; ++ch) {
        float xv = (ch & 1) ? hi16(vv[ch >> 1]) : lo16(vv[ch >> 1]);
        acc[ch] = fmaf(wv, xv, acc[ch]);
      }
    }
  }
#pragma unroll
  for (int ch = 0; ch < 16; ++ch) xds[p * 129 + (gg << 4) + ch] = acc[ch];
  __syncthreads();
  for (int i = 0; i < 16; ++i) {
    int lin = (i << 8) + tid;
    int cc = lin >> 5, pp2 = lin & 31;
    xs[(((long)(b << 7) + cc) << 14) + l0 + pp2] = fbf(xds[pp2 * 129 + cc]);
  }
  for (int task = tid; task < 320; task += 256) {
    int p2 = task / 10, r = task - p2 * 10;
    const float* wr = xpws + (r << 7);
    const float* xr = xds + p2 * 129;
    float sacc = 0.f;
#pragma unroll 8
    for (int cc = 0; cc < 128; ++cc) sacc = fmaf(wr[cc], xr[cc], sacc);
    xdbl[p2 * 12 + r] = sacc;
  }
  __syncthreads();
  for (int i = 0; i < 16; ++i) {
    int lin = (i << 8) + tid;
    int dd = lin >> 5, pp2 = lin & 31;
    const float* xb = xdbl + pp2 * 12;
    const float* wd = dtws + (dd << 3);
    float sacc = 0.f;
#pragma unroll
    for (int r = 0; r < 8; ++r) sacc = fmaf(wd[r], xb[r], sacc);
    dts[(((long)(b << 7) + dd) << 14) + l0 + pp2] = fbf(sacc);
  }
  if (tid < 32) {
    Bsb[((long)b << 14) + l0 + tid] = xdbl[tid * 12 + 8];
    Csb[((long)b << 14) + l0 + tid] = xdbl[tid * 12 + 9];
  }
}

// ---- K5: selective scan, 1024 thr x 16 elem, recompute pass 2 (no spill) ---
__global__ __launch_bounds__(1024) void k_scan(u16* __restrict__ xy,
                                               const u16* __restrict__ dts16,
                                               const float* __restrict__ Bsb,
                                               const float* __restrict__ Csb,
                                               const float* __restrict__ A_logs,
                                               const float* __restrict__ Dsv,
                                               const float* __restrict__ dtbv) {
  __shared__ float sp[1024], se[1024];
  int bd = blockIdx.x;
  int b = bd >> 7, d = bd & 127;
  float Ad = -__expf(A_logs[d]);
  float dtb = dtbv[d];
  float Dd = Dsv[d];
  int t = threadIdx.x;
  long base = ((long)bd << 14) + (t << 4);
  long bb = ((long)b << 14) + (t << 4);
  const uint4* pz4 = (const uint4*)(dts16 + base);
  const uint4* px4 = (const uint4*)(xy + base);
  const float4* pB = (const float4*)(Bsb + bb);
  const float4* pC = (const float4*)(Csb + bb);
  uint4 zA = pz4[0], zB = pz4[1];
  uint4 xA = px4[0], xB = px4[1];
  u32 zw[8] = {zA.x, zA.y, zA.z, zA.w, zB.x, zB.y, zB.z, zB.w};
  u32 xw[8] = {xA.x, xA.y, xA.z, xA.w, xB.x, xB.y, xB.z, xB.w};
  float h = 0.f, P = 1.f;
#pragma unroll
  for (int q = 0; q < 4; ++q) {
    float4 B4 = pB[q];
    float Bq[4] = {B4.x, B4.y, B4.z, B4.w};
#pragma unroll
    for (int j = 0; j < 4; ++j) {
      int k = (q << 2) + j;
      float z = (k & 1) ? hi16(zw[k >> 1]) : lo16(zw[k >> 1]);
      float xv = (k & 1) ? hi16(xw[k >> 1]) : lo16(xw[k >> 1]);
      float delta = softplusf(z + dtb);
      float a = __expf(delta * Ad);
      h = fmaf(a, h, delta * Bq[j] * xv);
      P *= a;
    }
  }
  sp[t] = P; se[t] = h;
  __syncthreads();
  for (int off = 1; off < 1024; off <<= 1) {
    float pc = sp[t], ec = se[t];
    float pp = 1.f, ep = 0.f;
    bool actv = (t >= off);
    if (actv) { pp = sp[t - off]; ep = se[t - off]; }
    __syncthreads();
    if (actv) { sp[t] = pp * pc; se[t] = fmaf(pc, ep, ec); }
    __syncthreads();
  }
  h = (t == 0) ? 0.f : se[t - 1];
  u32 ypk[8];
#pragma unroll
  for (int q = 0; q < 4; ++q) {
    float4 B4 = pB[q];
    float4 C4 = pC[q];
    float Bq[4] = {B4.x, B4.y, B4.z, B4.w};
    float Cq[4] = {C4.x, C4.y, C4.z, C4.w};
#pragma unroll
    for (int j = 0; j < 4; ++j) {
      int k = (q << 2) + j;
      float z = (k & 1) ? hi16(zw[k >> 1]) : lo16(zw[k >> 1]);
      float xv = (k & 1) ? hi16(xw[k >> 1]) : lo16(xw[k >> 1]);
      float delta = softplusf(z + dtb);
      float a = __expf(delta * Ad);
      h = fmaf(a, h, delta * Bq[j] * xv);
      u16 yb = fbf(fmaf(Dd, xv, h * Cq[j]));
      if ((k & 1) == 0) ypk[k >> 1] = yb; else ypk[k >> 1] |= (u32)yb << 16;
    }
  }
  uint4* py = (uint4*)(xy + base);
  py[0] = make_uint4(ypk[0], ypk[1], ypk[2], ypk[3]);
  py[1] = make_uint4(ypk[4], ypk[5], ypk[6], ypk[7]);
}

// ---- K6a: per-pixel mean/rstd of y over channels ---------------------------
__global__ __launch_bounds__(256) void k_stats(const u16* __restrict__ y,
                                               float* __restrict__ meanb,
                                               float* __restrict__ rstdb) {
  int pg = (blockIdx.x << 8) + threadIdx.x;
  int b = pg >> 14, l = pg & 16383;
  const u16* py = y + ((long)b << 21) + l;
  float s = 0.f, ss = 0.f;
  for (int c = 0; c < 128; ++c) { float v = bfu(py[(long)c << 14]); s += v; ss = fmaf(v, v, ss); }
  float m = s * (1.f / 128.f);
  meanb[pg] = m;
  rstdb[pg] = rsqrtf(ss * (1.f / 128.f) - m * m + 1e-6f);
}

// ---- K6b: s1[o]=sum W2*beta, s2[o]=sum W2*gamma ----------------------------
__global__ void k_sums(const float* __restrict__ W2, const float* __restrict__ g,
                       const float* __restrict__ bln, float* __restrict__ s12) {
  int o = threadIdx.x;
  float s1 = 0.f, s2 = 0.f;
  for (int c = 0; c < 128; ++c) {
    float w = W2[(o << 7) + c];
    s1 = fmaf(w, bln[c], s1);
    s2 = fmaf(w, g[c], s2);
  }
  s12[o] = s1;
  s12[128 + o] = s2;
}

// ---- K7: out_proj GEMM with LayerNorm folded into epilogue (f32 out) -------
__global__ __launch_bounds__(256) void k_outproj(const u16* __restrict__ y,
                                                 const float* __restrict__ W2,
                                                 const float* __restrict__ g,
                                                 const float* __restrict__ meanb,
                                                 const float* __restrict__ rstdb,
                                                 const float* __restrict__ s12,
                                                 float* __restrict__ out) {
  __shared__ __align__(16) u16 Wt[128 * 136];  // [c][o], bf16 of W2*gamma
  __shared__ __align__(16) u16 Ys[128 * 72];   // [c][p], bf16 y
  __shared__ float gs[128], s1s[128], s2s[128];
  int tid = threadIdx.x;
  if (tid < 128) { gs[tid] = g[tid]; s1s[tid] = s12[tid]; s2s[tid] = s12[128 + tid]; }
  __syncthreads();
  int b = blockIdx.x >> 8;
  int l0 = (blockIdx.x & 255) << 6;
  for (int i = 0; i < 64; ++i) {
    int lin = (i << 8) + tid;
    int o = lin >> 7, c = lin & 127;
    Wt[c * 136 + o] = fbf(W2[lin] * gs[c]);
  }
  for (int i = 0; i < 32; ++i) {
    int lin = (i << 8) + tid;
    int c = lin >> 6, p = lin & 63;
    Ys[c * 72 + p] = y[(((b << 7) + c) << 14) + l0 + p];
  }
  __syncthreads();
  int tx = tid & 15, ty = tid >> 4;
  int o0 = tx << 3, p0 = ty << 2;
  float acc[8][4] = {};
  for (int c = 0; c < 128; ++c) {
    uint4 aw = *(const uint4*)&Wt[c * 136 + o0];
    uint2 bw = *(const uint2*)&Ys[c * 72 + p0];
    float a[8], bv[4];
    a[0] = lo16(aw.x); a[1] = hi16(aw.x);
    a[2] = lo16(aw.y); a[3] = hi16(aw.y);
    a[4] = lo16(aw.z); a[5] = hi16(aw.z);
    a[6] = lo16(aw.w); a[7] = hi16(aw.w);
    bv[0] = lo16(bw.x); bv[1] = hi16(bw.x);
    bv[2] = lo16(bw.y); bv[3] = hi16(bw.y);
#pragma unroll
    for (int i = 0; i < 8; ++i)
#pragma unroll
      for (int j = 0; j < 4; ++j) acc[i][j] = fmaf(a[i], bv[j], acc[i][j]);
  }
  float4 m4 = *(const float4*)&meanb[((long)b << 14) + l0 + p0];
  float4 r4 = *(const float4*)&rstdb[((long)b << 14) + l0 + p0];
  float mm[4] = {m4.x, m4.y, m4.z, m4.w};
  float rr[4] = {r4.x, r4.y, r4.z, r4.w};
#pragma unroll
  for (int i = 0; i < 8; ++i) {
    int o = o0 + i;
    float s1v = s1s[o], s2v = s2s[o];
    float4 sv;
    sv.x = fmaf(rr[0], acc[i][0] - mm[0] * s2v, s1v);
    sv.y = fmaf(rr[1], acc[i][1] - mm[1] * s2v, s1v);
    sv.z = fmaf(rr[2], acc[i][2] - mm[2] * s2v, s1v);
    sv.w = fmaf(rr[3], acc[i][3] - mm[3] * s2v, s1v);
    *(float4*)&out[(((long)(b << 7) + o) << 14) + l0 + p0] = sv;
  }
}

extern "C" void kernel_launch(void* const* d_in, const int* in_sizes, int n_in,
                              void* d_out, int out_size, void* d_ws, size_t ws_size,
                              hipStream_t stream) {
  const float* x         = (const float*)d_in[0];
  const float* in_proj_w = (const float*)d_in[1];
  const float* conv2d_w  = (const float*)d_in[2];
  const float* conv2d_b  = (const float*)d_in[3];
  const float* dw_w      = (const float*)d_in[4];
  const float* dw_b      = (const float*)d_in[5];
  const float* dw_ln_g   = (const float*)d_in[6];
  const float* dw_ln_b   = (const float*)d_in[7];
  const float* off_w     = (const float*)d_in[8];
  const float* off_b     = (const float*)d_in[9];
  const float* x_proj_w  = (const float*)d_in[10];
  const float* dt_w      = (const float*)d_in[11];
  const float* dt_b      = (const float*)d_in[12];
  const float* A_logs    = (const float*)d_in[13];
  const float* Ds        = (const float*)d_in[14];
  const float* out_ln_g  = (const float*)d_in[15];
  const float* out_ln_b  = (const float*)d_in[16];
  const float* out_proj_w= (const float*)d_in[17];
  float* out = (float*)d_out;

  // bf16 internal buffers (u16), 8388608 elems each = 16 MiB
  u16* A  = (u16*)d_ws;            // xin_cl -> x1_cl -> xs[b,c,l] -> y[b,c,l]
  u16* Bx = A + 8388608;           // xc_cl
  u16* Dd = Bx + 8388608;          // dts[b,c,l]
  float* offs  = (float*)(Dd + 8388608);  // (B,L,16)
  float* Bsb   = offs + 1048576;
  float* Csb   = Bsb + 65536;
  float* meanb = Csb + 65536;
  float* rstdb = meanb + 65536;
  float* s12   = rstdb + 65536;

  hipLaunchKernelGGL(k_inproj, dim3(1024), dim3(256), 0, stream, x, in_proj_w, A);
  hipLaunchKernelGGL(k_dwconv, dim3(4096), dim3(256), 0, stream, A, conv2d_w, conv2d_b, Bx, 1);
  hipLaunchKernelGGL(k_dwconv, dim3(4096), dim3(256), 0, stream, Bx, dw_w, dw_b, A, 0);
  hipLaunchKernelGGL(k_offset, dim3(256), dim3(256), 0, stream, A, dw_ln_g, dw_ln_b, off_w, off_b, offs);
  hipLaunchKernelGGL(k_dcn, dim3(2048), dim3(256), 0, stream, Bx, offs, x_proj_w, dt_w, A, Dd, Bsb, Csb);
  hipLaunchKernelGGL(k_scan, dim3(512), dim3(1024), 0, stream, A, Dd, Bsb, Csb, A_logs, Ds, dt_b);
  hipLaunchKernelGGL(k_stats, dim3(256), dim3(256), 0, stream, A, meanb, rstdb);
  hipLaunchKernelGGL(k_sums, dim3(1), dim3(128), 0, stream, out_proj_w, out_ln_g, out_ln_b, s12);
  hipLaunchKernelGGL(k_outproj, dim3(1024), dim3(256), 0, stream, A, out_proj_w, out_ln_g, meanb, rstdb, s12, out);
}

// Round 5
// 312.402 us; speedup vs baseline: 1.4629x; 1.1499x over previous
//
#include <hip/hip_runtime.h>
#include <hip/hip_bf16.h>

typedef unsigned short u16;
typedef unsigned int u32;

__device__ __forceinline__ float bfu(u16 u) { return __uint_as_float(((u32)u) << 16); }
__device__ __forceinline__ u16 fbf(float f) {
  __hip_bfloat16 h = __float2bfloat16(f);
  return *reinterpret_cast<u16*>(&h);
}
// cheap softplus: 2 transcendentals; abs err ~1e-7, invisible at bf16 scale
__device__ __forceinline__ float softplusf(float z) {
  float t = __expf(z);
  return (z > 20.f) ? z : __logf(1.f + t);
}
__device__ __forceinline__ float lo16(u32 p) { return __uint_as_float(p << 16); }
__device__ __forceinline__ float hi16(u32 p) { return __uint_as_float(p & 0xffff0000u); }

// ---- K1: in_proj GEMM: out_cl[b,l,o] = sum_c W[o,c] * x[b,c,l] ------------
__global__ __launch_bounds__(256) void k_inproj(const float* __restrict__ X,
                                                const float* __restrict__ W,
                                                u16* __restrict__ out) {
  __shared__ __align__(16) u16 Wt[128 * 136];  // [c][o]
  __shared__ __align__(16) u16 Xs[128 * 72];   // [c][p]
  int tid = threadIdx.x;
  int b = blockIdx.x >> 8;
  int l0 = (blockIdx.x & 255) << 6;
  for (int i = 0; i < 64; ++i) {
    int lin = (i << 8) + tid;
    int o = lin >> 7, c = lin & 127;
    Wt[c * 136 + o] = fbf(W[lin]);
  }
  for (int i = 0; i < 32; ++i) {
    int lin = (i << 8) + tid;
    int c = lin >> 6, p = lin & 63;
    Xs[c * 72 + p] = fbf(X[(((b << 7) + c) << 14) + l0 + p]);
  }
  __syncthreads();
  int tx = tid & 15, ty = tid >> 4;
  int o0 = tx << 3, p0 = ty << 2;
  float acc[8][4] = {};
  for (int c = 0; c < 128; ++c) {
    uint4 aw = *(const uint4*)&Wt[c * 136 + o0];
    uint2 bw = *(const uint2*)&Xs[c * 72 + p0];
    float a[8], bv[4];
    a[0] = lo16(aw.x); a[1] = hi16(aw.x);
    a[2] = lo16(aw.y); a[3] = hi16(aw.y);
    a[4] = lo16(aw.z); a[5] = hi16(aw.z);
    a[6] = lo16(aw.w); a[7] = hi16(aw.w);
    bv[0] = lo16(bw.x); bv[1] = hi16(bw.x);
    bv[2] = lo16(bw.y); bv[3] = hi16(bw.y);
#pragma unroll
    for (int i = 0; i < 8; ++i)
#pragma unroll
      for (int j = 0; j < 4; ++j) acc[i][j] = fmaf(a[i], bv[j], acc[i][j]);
  }
#pragma unroll
  for (int j = 0; j < 4; ++j) {
    int l = l0 + p0 + j;
    ushort4 s0, s1;
    s0.x = fbf(acc[0][j]); s0.y = fbf(acc[1][j]);
    s0.z = fbf(acc[2][j]); s0.w = fbf(acc[3][j]);
    s1.x = fbf(acc[4][j]); s1.y = fbf(acc[5][j]);
    s1.z = fbf(acc[6][j]); s1.w = fbf(acc[7][j]);
    u16* po = out + ((((long)(b << 14) + l)) << 7) + o0;
    *(ushort4*)po = s0;
    *(ushort4*)(po + 4) = s1;
  }
}

// ---- K2/K3a: depthwise 3x3 conv, channels-last, optional SiLU --------------
__global__ __launch_bounds__(256) void k_dwconv(const u16* __restrict__ in,
                                                const float* __restrict__ w9,
                                                const float* __restrict__ bias,
                                                u16* __restrict__ out, int act) {
  __shared__ float wsT[9][128];
  __shared__ float bs[128];
  int tid = threadIdx.x;
  for (int i = 0; i < 5; ++i) {
    int lin = (i << 8) + tid;
    if (lin < 1152) { int c = lin / 9, k = lin - 9 * c; wsT[k][c] = w9[lin]; }
  }
  if (tid < 128) bs[tid] = bias[tid];
  __syncthreads();
  int blk = blockIdx.x;
  int b = blk >> 10;
  int s = blk & 1023;
  int h = s >> 3;
  int w = ((s & 7) << 4) + (tid >> 4);
  int c0 = (tid & 15) << 3;
  const u16* bbase = in + ((long)b << 21);
  float acc[8];
  {
    float4 b0 = *(const float4*)&bs[c0];
    float4 b1 = *(const float4*)&bs[c0 + 4];
    acc[0] = b0.x; acc[1] = b0.y; acc[2] = b0.z; acc[3] = b0.w;
    acc[4] = b1.x; acc[5] = b1.y; acc[6] = b1.z; acc[7] = b1.w;
  }
#pragma unroll
  for (int ky = -1; ky <= 1; ++ky) {
    int y = h + ky;
    if ((unsigned)y >= 128u) continue;
#pragma unroll
    for (int kx = -1; kx <= 1; ++kx) {
      int x = w + kx;
      if ((unsigned)x >= 128u) continue;
      int k = (ky + 1) * 3 + (kx + 1);
      uint4 v = *(const uint4*)(bbase + ((((y << 7) + x)) << 7) + c0);
      float4 w0 = *(const float4*)&wsT[k][c0];
      float4 w1 = *(const float4*)&wsT[k][c0 + 4];
      u32 vv[4] = {v.x, v.y, v.z, v.w};
      float wf[8] = {w0.x, w0.y, w0.z, w0.w, w1.x, w1.y, w1.z, w1.w};
#pragma unroll
      for (int cc = 0; cc < 8; ++cc) {
        float xv = (cc & 1) ? hi16(vv[cc >> 1]) : lo16(vv[cc >> 1]);
        acc[cc] = fmaf(wf[cc], xv, acc[cc]);
      }
    }
  }
  if (act) {
#pragma unroll
    for (int cc = 0; cc < 8; ++cc) acc[cc] = acc[cc] / (1.f + __expf(-acc[cc]));
  }
  ushort4 s0, s1;
  s0.x = fbf(acc[0]); s0.y = fbf(acc[1]); s0.z = fbf(acc[2]); s0.w = fbf(acc[3]);
  s1.x = fbf(acc[4]); s1.y = fbf(acc[5]); s1.z = fbf(acc[6]); s1.w = fbf(acc[7]);
  u16* po = out + ((long)b << 21) + ((((h << 7) + w)) << 7) + c0;
  *(ushort4*)po = s0;
  *(ushort4*)(po + 4) = s1;
}

// ---- K3b: per-pixel LN + GELU + offset projection, channels-last -----------
__global__ __launch_bounds__(256) void k_offset(const u16* __restrict__ x1,
                                                const float* __restrict__ g,
                                                const float* __restrict__ bt,
                                                const float* __restrict__ offw,
                                                const float* __restrict__ offb,
                                                float* __restrict__ offs) {
  __shared__ float Wo[16 * 128];
  __shared__ float gs[128], bsh[128];
  int tid = threadIdx.x;
  if (tid < 128) { gs[tid] = g[tid]; bsh[tid] = bt[tid]; }
  for (int i = 0; i < 8; ++i) { int idx = (i << 8) + tid; Wo[idx] = offw[idx]; }
  __syncthreads();
  int pg = (blockIdx.x << 8) + tid;  // b*L + l
  const uint4* px = (const uint4*)(x1 + ((long)pg << 7));
  float s = 0.f, ss = 0.f;
  for (int i = 0; i < 16; ++i) {
    uint4 v = px[i];
    u32 vv[4] = {v.x, v.y, v.z, v.w};
#pragma unroll
    for (int cc = 0; cc < 8; ++cc) {
      float xv = (cc & 1) ? hi16(vv[cc >> 1]) : lo16(vv[cc >> 1]);
      s += xv; ss = fmaf(xv, xv, ss);
    }
  }
  float mean = s * (1.f / 128.f);
  float var = ss * (1.f / 128.f) - mean * mean;
  float rstd = rsqrtf(var + 1e-6f);
  float acc[16];
#pragma unroll
  for (int j = 0; j < 16; ++j) acc[j] = offb[j];
  for (int i = 0; i < 16; ++i) {
    uint4 v = px[i];  // L1 hit
    u32 vv[4] = {v.x, v.y, v.z, v.w};
#pragma unroll
    for (int cc = 0; cc < 8; ++cc) {
      int c = (i << 3) + cc;
      float xv = (cc & 1) ? hi16(vv[cc >> 1]) : lo16(vv[cc >> 1]);
      float xn = fmaf((xv - mean) * rstd, gs[c], bsh[c]);
      float ge = 0.5f * xn * (1.f + erff(xn * 0.70710678118f));
#pragma unroll
      for (int j = 0; j < 16; ++j) acc[j] = fmaf(Wo[j * 128 + c], ge, acc[j]);
    }
  }
  float* po = offs + ((long)pg << 4);
#pragma unroll
  for (int j = 0; j < 4; ++j)
    *(float4*)&po[j << 2] = make_float4(acc[4 * j], acc[4 * j + 1], acc[4 * j + 2], acc[4 * j + 3]);
}

// ---- K4: DCN bilinear gather (channels-last) + x_proj + dt_w fused ---------
__global__ __launch_bounds__(256) void k_dcn(const u16* __restrict__ xc,
                                             const float* __restrict__ offs,
                                             const float* __restrict__ xpw,
                                             const float* __restrict__ dtw,
                                             u16* __restrict__ xs,
                                             u16* __restrict__ dts,
                                             float* __restrict__ Bsb,
                                             float* __restrict__ Csb) {
  __shared__ float xds[32 * 129];
  __shared__ float xdbl[32 * 12];
  __shared__ float xpws[1280];
  __shared__ float dtws[1024];
  int tid = threadIdx.x;
  for (int i = 0; i < 5; ++i) { int idx = (i << 8) + tid; if (idx < 1280) xpws[idx] = xpw[idx]; }
  for (int i = 0; i < 4; ++i) { int idx = (i << 8) + tid; dtws[idx] = dtw[idx]; }
  int blk = blockIdx.x;
  int b = blk >> 9;
  int l0 = (blk & 511) << 5;
  int p = tid >> 3, gg = tid & 7;
  int l = l0 + p, hh = l >> 7, ww = l & 127;
  float2 off = *(const float2*)&offs[(((long)(b << 14) + l) << 4) + (gg << 1)];
  float px = (float)ww + off.x, py = (float)hh + off.y;
  float x0f = floorf(px), y0f = floorf(py);
  float wx = px - x0f, wy = py - y0f;
  int ix = (int)x0f, iy = (int)y0f;
  float acc[16];
#pragma unroll
  for (int ch = 0; ch < 16; ++ch) acc[ch] = 0.f;
  const u16* bbase = xc + ((long)b << 21) + (gg << 4);
  int xi[4] = {ix, ix + 1, ix, ix + 1};
  int yi[4] = {iy, iy, iy + 1, iy + 1};
  float wt4[4] = {(1.f - wy) * (1.f - wx), (1.f - wy) * wx, wy * (1.f - wx), wy * wx};
#pragma unroll
  for (int t = 0; t < 4; ++t) {
    if (wt4[t] != 0.f && (unsigned)yi[t] < 128u && (unsigned)xi[t] < 128u) {
      const u16* pp = bbase + ((((yi[t] << 7) + xi[t])) << 7);
      uint4 v0 = *(const uint4*)pp;
      uint4 v1 = *(const uint4*)(pp + 8);
      float wv = wt4[t];
      u32 vv[8] = {v0.x, v0.y, v0.z, v0.w, v1.x, v1.y, v1.z, v1.w};
#pragma unroll
      for (int ch = 0; ch < 16; ++ch) {
        float xv = (ch & 1) ? hi16(vv[ch >> 1]) : lo16(vv[ch >> 1]);
        acc[ch] = fmaf(wv, xv, acc[ch]);
      }
    }
  }
#pragma unroll
  for (int ch = 0; ch < 16; ++ch) xds[p * 129 + (gg << 4) + ch] = acc[ch];
  __syncthreads();
  for (int i = 0; i < 16; ++i) {
    int lin = (i << 8) + tid;
    int cc = lin >> 5, pp2 = lin & 31;
    xs[(((long)(b << 7) + cc) << 14) + l0 + pp2] = fbf(xds[pp2 * 129 + cc]);
  }
  for (int task = tid; task < 320; task += 256) {
    int p2 = task / 10, r = task - p2 * 10;
    const float* wr = xpws + (r << 7);
    const float* xr = xds + p2 * 129;
    float sacc = 0.f;
#pragma unroll 8
    for (int cc = 0; cc < 128; ++cc) sacc = fmaf(wr[cc], xr[cc], sacc);
    xdbl[p2 * 12 + r] = sacc;
  }
  __syncthreads();
  for (int i = 0; i < 16; ++i) {
    int lin = (i << 8) + tid;
    int dd = lin >> 5, pp2 = lin & 31;
    const float* xb = xdbl + pp2 * 12;
    const float* wd = dtws + (dd << 3);
    float sacc = 0.f;
#pragma unroll
    for (int r = 0; r < 8; ++r) sacc = fmaf(wd[r], xb[r], sacc);
    dts[(((long)(b << 7) + dd) << 14) + l0 + pp2] = fbf(sacc);
  }
  if (tid < 32) {
    Bsb[((long)b << 14) + l0 + tid] = xdbl[tid * 12 + 8];
    Csb[((long)b << 14) + l0 + tid] = xdbl[tid * 12 + 9];
  }
}

// ---- K5: selective scan, shfl-based block scan, cheap softplus -------------
__global__ __launch_bounds__(1024) void k_scan(u16* __restrict__ xy,
                                               const u16* __restrict__ dts16,
                                               const float* __restrict__ Bsb,
                                               const float* __restrict__ Csb,
                                               const float* __restrict__ A_logs,
                                               const float* __restrict__ Dsv,
                                               const float* __restrict__ dtbv) {
  __shared__ float swp[16], swe[16];
  int bd = blockIdx.x;
  int b = bd >> 7, d = bd & 127;
  float Ad = -__expf(A_logs[d]);
  float dtb = dtbv[d];
  float Dd = Dsv[d];
  int t = threadIdx.x;
  int lane = t & 63, wid = t >> 6;
  long base = ((long)bd << 14) + (t << 4);
  long bb = ((long)b << 14) + (t << 4);
  const uint4* pz4 = (const uint4*)(dts16 + base);
  const uint4* px4 = (const uint4*)(xy + base);
  const float4* pB = (const float4*)(Bsb + bb);
  const float4* pC = (const float4*)(Csb + bb);
  uint4 zA = pz4[0], zB = pz4[1];
  uint4 xA = px4[0], xB = px4[1];
  u32 zw[8] = {zA.x, zA.y, zA.z, zA.w, zB.x, zB.y, zB.z, zB.w};
  u32 xw[8] = {xA.x, xA.y, xA.z, xA.w, xB.x, xB.y, xB.z, xB.w};
  float E = 0.f, P = 1.f;
#pragma unroll
  for (int q = 0; q < 4; ++q) {
    float4 B4 = pB[q];
    float Bq[4] = {B4.x, B4.y, B4.z, B4.w};
#pragma unroll
    for (int j = 0; j < 4; ++j) {
      int k = (q << 2) + j;
      float z = (k & 1) ? hi16(zw[k >> 1]) : lo16(zw[k >> 1]);
      float xv = (k & 1) ? hi16(xw[k >> 1]) : lo16(xw[k >> 1]);
      float delta = softplusf(z + dtb);
      float a = __expf(delta * Ad);
      E = fmaf(a, E, delta * Bq[j] * xv);
      P *= a;
    }
  }
  // wave-level inclusive scan of (P,E) under composition h -> P*h + E
#pragma unroll
  for (int off = 1; off < 64; off <<= 1) {
    float Pp = __shfl_up(P, off);
    float Ep = __shfl_up(E, off);
    if (lane >= off) { E = fmaf(P, Ep, E); P *= Pp; }
  }
  if (lane == 63) { swp[wid] = P; swe[wid] = E; }
  __syncthreads();
  if (t < 16) {
    float p2 = swp[t], e2 = swe[t];
#pragma unroll
    for (int off = 1; off < 16; off <<= 1) {
      float pp = __shfl_up(p2, off);
      float ee = __shfl_up(e2, off);
      if (t >= off) { e2 = fmaf(p2, ee, e2); p2 *= pp; }
    }
    swp[t] = p2; swe[t] = e2;
  }
  __syncthreads();
  float hw = (wid == 0) ? 0.f : swe[wid - 1];  // h at wave start (h0=0)
  float Pex = __shfl_up(P, 1);
  float Eex = __shfl_up(E, 1);
  if (lane == 0) { Pex = 1.f; Eex = 0.f; }
  float h = fmaf(Pex, hw, Eex);  // h at this thread's segment start
  u32 ypk[8];
#pragma unroll
  for (int q = 0; q < 4; ++q) {
    float4 B4 = pB[q];
    float4 C4 = pC[q];
    float Bq[4] = {B4.x, B4.y, B4.z, B4.w};
    float Cq[4] = {C4.x, C4.y, C4.z, C4.w};
#pragma unroll
    for (int j = 0; j < 4; ++j) {
      int k = (q << 2) + j;
      float z = (k & 1) ? hi16(zw[k >> 1]) : lo16(zw[k >> 1]);
      float xv = (k & 1) ? hi16(xw[k >> 1]) : lo16(xw[k >> 1]);
      float delta = softplusf(z + dtb);
      float a = __expf(delta * Ad);
      h = fmaf(a, h, delta * Bq[j] * xv);
      u16 yb = fbf(fmaf(Dd, xv, h * Cq[j]));
      if ((k & 1) == 0) ypk[k >> 1] = yb; else ypk[k >> 1] |= (u32)yb << 16;
    }
  }
  uint4* py = (uint4*)(xy + base);
  py[0] = make_uint4(ypk[0], ypk[1], ypk[2], ypk[3]);
  py[1] = make_uint4(ypk[4], ypk[5], ypk[6], ypk[7]);
}

// ---- K6b: s1[o]=sum W2*beta, s2[o]=sum W2*gamma ----------------------------
__global__ void k_sums(const float* __restrict__ W2, const float* __restrict__ g,
                       const float* __restrict__ bln, float* __restrict__ s12) {
  int o = threadIdx.x;
  float s1 = 0.f, s2 = 0.f;
  for (int c = 0; c < 128; ++c) {
    float w = W2[(o << 7) + c];
    s1 = fmaf(w, bln[c], s1);
    s2 = fmaf(w, g[c], s2);
  }
  s12[o] = s1;
  s12[128 + o] = s2;
}

// ---- K7: out_proj GEMM + fused per-pixel LN stats in the c-loop ------------
__global__ __launch_bounds__(256) void k_outproj(const u16* __restrict__ y,
                                                 const float* __restrict__ W2,
                                                 const float* __restrict__ g,
                                                 const float* __restrict__ s12,
                                                 float* __restrict__ out) {
  __shared__ __align__(16) u16 Wt[128 * 136];  // [c][o], bf16 of W2*gamma
  __shared__ __align__(16) u16 Ys[128 * 72];   // [c][p], bf16 y
  __shared__ float gs[128], s1s[128], s2s[128];
  int tid = threadIdx.x;
  if (tid < 128) { gs[tid] = g[tid]; s1s[tid] = s12[tid]; s2s[tid] = s12[128 + tid]; }
  __syncthreads();
  int b = blockIdx.x >> 8;
  int l0 = (blockIdx.x & 255) << 6;
  for (int i = 0; i < 64; ++i) {
    int lin = (i << 8) + tid;
    int o = lin >> 7, c = lin & 127;
    Wt[c * 136 + o] = fbf(W2[lin] * gs[c]);
  }
  for (int i = 0; i < 32; ++i) {
    int lin = (i << 8) + tid;
    int c = lin >> 6, p = lin & 63;
    Ys[c * 72 + p] = y[(((b << 7) + c) << 14) + l0 + p];
  }
  __syncthreads();
  int tx = tid & 15, ty = tid >> 4;
  int o0 = tx << 3, p0 = ty << 2;
  float acc[8][4] = {};
  float sy[4] = {}, syy[4] = {};
  for (int c = 0; c < 128; ++c) {
    uint4 aw = *(const uint4*)&Wt[c * 136 + o0];
    uint2 bw = *(const uint2*)&Ys[c * 72 + p0];
    float a[8], bv[4];
    a[0] = lo16(aw.x); a[1] = hi16(aw.x);
    a[2] = lo16(aw.y); a[3] = hi16(aw.y);
    a[4] = lo16(aw.z); a[5] = hi16(aw.z);
    a[6] = lo16(aw.w); a[7] = hi16(aw.w);
    bv[0] = lo16(bw.x); bv[1] = hi16(bw.x);
    bv[2] = lo16(bw.y); bv[3] = hi16(bw.y);
#pragma unroll
    for (int j = 0; j < 4; ++j) { sy[j] += bv[j]; syy[j] = fmaf(bv[j], bv[j], syy[j]); }
#pragma unroll
    for (int i = 0; i < 8; ++i)
#pragma unroll
      for (int j = 0; j < 4; ++j) acc[i][j] = fmaf(a[i], bv[j], acc[i][j]);
  }
  float mm[4], rr[4];
#pragma unroll
  for (int j = 0; j < 4; ++j) {
    mm[j] = sy[j] * (1.f / 128.f);
    rr[j] = rsqrtf(syy[j] * (1.f / 128.f) - mm[j] * mm[j] + 1e-6f);
  }
#pragma unroll
  for (int i = 0; i < 8; ++i) {
    int o = o0 + i;
    float s1v = s1s[o], s2v = s2s[o];
    float4 sv;
    sv.x = fmaf(rr[0], acc[i][0] - mm[0] * s2v, s1v);
    sv.y = fmaf(rr[1], acc[i][1] - mm[1] * s2v, s1v);
    sv.z = fmaf(rr[2], acc[i][2] - mm[2] * s2v, s1v);
    sv.w = fmaf(rr[3], acc[i][3] - mm[3] * s2v, s1v);
    *(float4*)&out[(((long)(b << 7) + o) << 14) + l0 + p0] = sv;
  }
}

extern "C" void kernel_launch(void* const* d_in, const int* in_sizes, int n_in,
                              void* d_out, int out_size, void* d_ws, size_t ws_size,
                              hipStream_t stream) {
  const float* x         = (const float*)d_in[0];
  const float* in_proj_w = (const float*)d_in[1];
  const float* conv2d_w  = (const float*)d_in[2];
  const float* conv2d_b  = (const float*)d_in[3];
  const float* dw_w      = (const float*)d_in[4];
  const float* dw_b      = (const float*)d_in[5];
  const float* dw_ln_g   = (const float*)d_in[6];
  const float* dw_ln_b   = (const float*)d_in[7];
  const float* off_w     = (const float*)d_in[8];
  const float* off_b     = (const float*)d_in[9];
  const float* x_proj_w  = (const float*)d_in[10];
  const float* dt_w      = (const float*)d_in[11];
  const float* dt_b      = (const float*)d_in[12];
  const float* A_logs    = (const float*)d_in[13];
  const float* Ds        = (const float*)d_in[14];
  const float* out_ln_g  = (const float*)d_in[15];
  const float* out_ln_b  = (const float*)d_in[16];
  const float* out_proj_w= (const float*)d_in[17];
  float* out = (float*)d_out;

  u16* A  = (u16*)d_ws;            // xin_cl -> x1_cl -> xs[b,c,l] -> y[b,c,l]
  u16* Bx = A + 8388608;           // xc_cl
  u16* Dd = Bx + 8388608;          // dts[b,c,l]
  float* offs  = (float*)(Dd + 8388608);  // (B,L,16)
  float* Bsb   = offs + 1048576;
  float* Csb   = Bsb + 65536;
  float* s12   = Csb + 65536;

  hipLaunchKernelGGL(k_inproj, dim3(1024), dim3(256), 0, stream, x, in_proj_w, A);
  hipLaunchKernelGGL(k_dwconv, dim3(4096), dim3(256), 0, stream, A, conv2d_w, conv2d_b, Bx, 1);
  hipLaunchKernelGGL(k_dwconv, dim3(4096), dim3(256), 0, stream, Bx, dw_w, dw_b, A, 0);
  hipLaunchKernelGGL(k_offset, dim3(256), dim3(256), 0, stream, A, dw_ln_g, dw_ln_b, off_w, off_b, offs);
  hipLaunchKernelGGL(k_dcn, dim3(2048), dim3(256), 0, stream, Bx, offs, x_proj_w, dt_w, A, Dd, Bsb, Csb);
  hipLaunchKernelGGL(k_scan, dim3(512), dim3(1024), 0, stream, A, Dd, Bsb, Csb, A_logs, Ds, dt_b);
  hipLaunchKernelGGL(k_sums, dim3(1), dim3(128), 0, stream, out_proj_w, out_ln_g, out_ln_b, s12);
  hipLaunchKernelGGL(k_outproj, dim3(1024), dim3(256), 0, stream, A, out_proj_w, out_ln_g, s12, out);
}

// Round 6
// 249.181 us; speedup vs baseline: 1.8341x; 1.2537x over previous
//
#include <hip/hip_runtime.h>
#include <hip/hip_bf16.h>

typedef unsigned short u16;
typedef unsigned int u32;
typedef __bf16 bf16x8 __attribute__((ext_vector_type(8)));
typedef float f32x4 __attribute__((ext_vector_type(4)));

__device__ __forceinline__ float bfu(u16 u) { return __uint_as_float(((u32)u) << 16); }
__device__ __forceinline__ u16 fbf(float f) {
  __hip_bfloat16 h = __float2bfloat16(f);
  return *reinterpret_cast<u16*>(&h);
}
__device__ __forceinline__ float softplusf(float z) {
  float t = __expf(z);
  return (z > 20.f) ? z : __logf(1.f + t);
}
__device__ __forceinline__ float lo16(u32 p) { return __uint_as_float(p << 16); }
__device__ __forceinline__ float hi16(u32 p) { return __uint_as_float(p & 0xffff0000u); }
__device__ __forceinline__ bf16x8 ld_bf8(const u16* p) {
  union { uint4 u; bf16x8 v; } c;
  c.u = *(const uint4*)p;
  return c.v;
}

// ---- K1: in_proj MFMA GEMM: out_cl[b,l,o] = sum_c W[o,c] * X[b,c,l] --------
// block: 128 o x 64 l, 4 waves; wave w: o in [32w,32w+32), all 64 l.
__global__ __launch_bounds__(256) void k_inproj(const float* __restrict__ X,
                                                const float* __restrict__ W,
                                                u16* __restrict__ out) {
  __shared__ __align__(16) u16 Ws[128 * 136];  // [o][c] bf16
  __shared__ __align__(16) u16 Xs[64 * 136];   // [l][c] bf16 (X^T tile)
  int tid = threadIdx.x;
  int b = blockIdx.x >> 8;
  int l0 = (blockIdx.x & 255) << 6;
  for (int i = 0; i < 16; ++i) {
    int idx = (i << 8) + tid;
    int o = idx >> 5, c4 = (idx & 31) << 2;
    float4 w4 = *(const float4*)&W[(o << 7) + c4];
    ushort4 s;
    s.x = fbf(w4.x); s.y = fbf(w4.y); s.z = fbf(w4.z); s.w = fbf(w4.w);
    *(ushort4*)&Ws[o * 136 + c4] = s;
  }
  for (int i = 0; i < 8; ++i) {
    int idx = (i << 8) + tid;
    int c = idx >> 4, lq = (idx & 15) << 2;
    float4 x4 = *(const float4*)&X[(((long)(b << 7) + c) << 14) + l0 + lq];
    Xs[(lq + 0) * 136 + c] = fbf(x4.x);
    Xs[(lq + 1) * 136 + c] = fbf(x4.y);
    Xs[(lq + 2) * 136 + c] = fbf(x4.z);
    Xs[(lq + 3) * 136 + c] = fbf(x4.w);
  }
  __syncthreads();
  int w = tid >> 6, lane = tid & 63;
  int mrow = lane & 15, quad = lane >> 4;
  f32x4 acc[2][4];
#pragma unroll
  for (int ot = 0; ot < 2; ++ot)
#pragma unroll
    for (int lt = 0; lt < 4; ++lt) acc[ot][lt] = (f32x4){0.f, 0.f, 0.f, 0.f};
#pragma unroll
  for (int kb = 0; kb < 4; ++kb) {
    int c0 = (kb << 5) + (quad << 3);
    bf16x8 af[2], bfr[4];
#pragma unroll
    for (int ot = 0; ot < 2; ++ot)
      af[ot] = ld_bf8(&Ws[((w << 5) + (ot << 4) + mrow) * 136 + c0]);
#pragma unroll
    for (int lt = 0; lt < 4; ++lt)
      bfr[lt] = ld_bf8(&Xs[((lt << 4) + mrow) * 136 + c0]);
#pragma unroll
    for (int ot = 0; ot < 2; ++ot)
#pragma unroll
      for (int lt = 0; lt < 4; ++lt)
        acc[ot][lt] = __builtin_amdgcn_mfma_f32_16x16x32_bf16(af[ot], bfr[lt], acc[ot][lt], 0, 0, 0);
  }
#pragma unroll
  for (int ot = 0; ot < 2; ++ot)
#pragma unroll
    for (int lt = 0; lt < 4; ++lt) {
      int l = l0 + (lt << 4) + mrow;                 // col = lane&15
      int o = (w << 5) + (ot << 4) + (quad << 2);    // row = quad*4+reg
      ushort4 s;
      s.x = fbf(acc[ot][lt][0]); s.y = fbf(acc[ot][lt][1]);
      s.z = fbf(acc[ot][lt][2]); s.w = fbf(acc[ot][lt][3]);
      *(ushort4*)&out[(((long)(b << 14) + l) << 7) + o] = s;
    }
}

// ---- K2/K3a: depthwise 3x3 conv, channels-last, optional SiLU --------------
__global__ __launch_bounds__(256) void k_dwconv(const u16* __restrict__ in,
                                                const float* __restrict__ w9,
                                                const float* __restrict__ bias,
                                                u16* __restrict__ out, int act) {
  __shared__ float wsT[9][128];
  __shared__ float bs[128];
  int tid = threadIdx.x;
  for (int i = 0; i < 5; ++i) {
    int lin = (i << 8) + tid;
    if (lin < 1152) { int c = lin / 9, k = lin - 9 * c; wsT[k][c] = w9[lin]; }
  }
  if (tid < 128) bs[tid] = bias[tid];
  __syncthreads();
  int blk = blockIdx.x;
  int b = blk >> 10;
  int s = blk & 1023;
  int h = s >> 3;
  int w = ((s & 7) << 4) + (tid >> 4);
  int c0 = (tid & 15) << 3;
  const u16* bbase = in + ((long)b << 21);
  float acc[8];
  {
    float4 b0 = *(const float4*)&bs[c0];
    float4 b1 = *(const float4*)&bs[c0 + 4];
    acc[0] = b0.x; acc[1] = b0.y; acc[2] = b0.z; acc[3] = b0.w;
    acc[4] = b1.x; acc[5] = b1.y; acc[6] = b1.z; acc[7] = b1.w;
  }
#pragma unroll
  for (int ky = -1; ky <= 1; ++ky) {
    int y = h + ky;
    if ((unsigned)y >= 128u) continue;
#pragma unroll
    for (int kx = -1; kx <= 1; ++kx) {
      int x = w + kx;
      if ((unsigned)x >= 128u) continue;
      int k = (ky + 1) * 3 + (kx + 1);
      uint4 v = *(const uint4*)(bbase + ((((y << 7) + x)) << 7) + c0);
      float4 w0 = *(const float4*)&wsT[k][c0];
      float4 w1 = *(const float4*)&wsT[k][c0 + 4];
      u32 vv[4] = {v.x, v.y, v.z, v.w};
      float wf[8] = {w0.x, w0.y, w0.z, w0.w, w1.x, w1.y, w1.z, w1.w};
#pragma unroll
      for (int cc = 0; cc < 8; ++cc) {
        float xv = (cc & 1) ? hi16(vv[cc >> 1]) : lo16(vv[cc >> 1]);
        acc[cc] = fmaf(wf[cc], xv, acc[cc]);
      }
    }
  }
  if (act) {
#pragma unroll
    for (int cc = 0; cc < 8; ++cc) acc[cc] = acc[cc] / (1.f + __expf(-acc[cc]));
  }
  ushort4 s0, s1;
  s0.x = fbf(acc[0]); s0.y = fbf(acc[1]); s0.z = fbf(acc[2]); s0.w = fbf(acc[3]);
  s1.x = fbf(acc[4]); s1.y = fbf(acc[5]); s1.z = fbf(acc[6]); s1.w = fbf(acc[7]);
  u16* po = out + ((long)b << 21) + ((((h << 7) + w)) << 7) + c0;
  *(ushort4*)po = s0;
  *(ushort4*)(po + 4) = s1;
}

// ---- K3b: per-pixel LN + GELU + offset projection, channels-last -----------
__global__ __launch_bounds__(256) void k_offset(const u16* __restrict__ x1,
                                                const float* __restrict__ g,
                                                const float* __restrict__ bt,
                                                const float* __restrict__ offw,
                                                const float* __restrict__ offb,
                                                float* __restrict__ offs) {
  __shared__ float Wo[16 * 128];
  __shared__ float gs[128], bsh[128];
  int tid = threadIdx.x;
  if (tid < 128) { gs[tid] = g[tid]; bsh[tid] = bt[tid]; }
  for (int i = 0; i < 8; ++i) { int idx = (i << 8) + tid; Wo[idx] = offw[idx]; }
  __syncthreads();
  int pg = (blockIdx.x << 8) + tid;  // b*L + l
  const uint4* px = (const uint4*)(x1 + ((long)pg << 7));
  float s = 0.f, ss = 0.f;
  for (int i = 0; i < 16; ++i) {
    uint4 v = px[i];
    u32 vv[4] = {v.x, v.y, v.z, v.w};
#pragma unroll
    for (int cc = 0; cc < 8; ++cc) {
      float xv = (cc & 1) ? hi16(vv[cc >> 1]) : lo16(vv[cc >> 1]);
      s += xv; ss = fmaf(xv, xv, ss);
    }
  }
  float mean = s * (1.f / 128.f);
  float var = ss * (1.f / 128.f) - mean * mean;
  float rstd = rsqrtf(var + 1e-6f);
  float acc[16];
#pragma unroll
  for (int j = 0; j < 16; ++j) acc[j] = offb[j];
  for (int i = 0; i < 16; ++i) {
    uint4 v = px[i];  // L1 hit
    u32 vv[4] = {v.x, v.y, v.z, v.w};
#pragma unroll
    for (int cc = 0; cc < 8; ++cc) {
      int c = (i << 3) + cc;
      float xv = (cc & 1) ? hi16(vv[cc >> 1]) : lo16(vv[cc >> 1]);
      float xn = fmaf((xv - mean) * rstd, gs[c], bsh[c]);
      float ge = 0.5f * xn * (1.f + erff(xn * 0.70710678118f));
#pragma unroll
      for (int j = 0; j < 16; ++j) acc[j] = fmaf(Wo[j * 128 + c], ge, acc[j]);
    }
  }
  float* po = offs + ((long)pg << 4);
#pragma unroll
  for (int j = 0; j < 4; ++j)
    *(float4*)&po[j << 2] = make_float4(acc[4 * j], acc[4 * j + 1], acc[4 * j + 2], acc[4 * j + 3]);
}

// ---- K4: DCN bilinear gather (channels-last) + x_proj + dt_w fused ---------
__global__ __launch_bounds__(256) void k_dcn(const u16* __restrict__ xc,
                                             const float* __restrict__ offs,
                                             const float* __restrict__ xpw,
                                             const float* __restrict__ dtw,
                                             u16* __restrict__ xs,
                                             u16* __restrict__ dts,
                                             float* __restrict__ Bsb,
                                             float* __restrict__ Csb) {
  __shared__ float xds[32 * 129];
  __shared__ float xdbl[32 * 12];
  __shared__ float xpws[1280];
  __shared__ float dtws[1024];
  int tid = threadIdx.x;
  for (int i = 0; i < 5; ++i) { int idx = (i << 8) + tid; if (idx < 1280) xpws[idx] = xpw[idx]; }
  for (int i = 0; i < 4; ++i) { int idx = (i << 8) + tid; dtws[idx] = dtw[idx]; }
  int blk = blockIdx.x;
  int b = blk >> 9;
  int l0 = (blk & 511) << 5;
  int p = tid >> 3, gg = tid & 7;
  int l = l0 + p, hh = l >> 7, ww = l & 127;
  float2 off = *(const float2*)&offs[(((long)(b << 14) + l) << 4) + (gg << 1)];
  float px = (float)ww + off.x, py = (float)hh + off.y;
  float x0f = floorf(px), y0f = floorf(py);
  float wx = px - x0f, wy = py - y0f;
  int ix = (int)x0f, iy = (int)y0f;
  float acc[16];
#pragma unroll
  for (int ch = 0; ch < 16; ++ch) acc[ch] = 0.f;
  const u16* bbase = xc + ((long)b << 21) + (gg << 4);
  int xi[4] = {ix, ix + 1, ix, ix + 1};
  int yi[4] = {iy, iy, iy + 1, iy + 1};
  float wt4[4] = {(1.f - wy) * (1.f - wx), (1.f - wy) * wx, wy * (1.f - wx), wy * wx};
#pragma unroll
  for (int t = 0; t < 4; ++t) {
    if (wt4[t] != 0.f && (unsigned)yi[t] < 128u && (unsigned)xi[t] < 128u) {
      const u16* pp = bbase + ((((yi[t] << 7) + xi[t])) << 7);
      uint4 v0 = *(const uint4*)pp;
      uint4 v1 = *(const uint4*)(pp + 8);
      float wv = wt4[t];
      u32 vv[8] = {v0.x, v0.y, v0.z, v0.w, v1.x, v1.y, v1.z, v1.w};
#pragma unroll
      for (int ch = 0; ch < 16; ++ch) {
        float xv = (ch & 1) ? hi16(vv[ch >> 1]) : lo16(vv[ch >> 1]);
        acc[ch] = fmaf(wv, xv, acc[ch]);
      }
    }
  }
#pragma unroll
  for (int ch = 0; ch < 16; ++ch) xds[p * 129 + (gg << 4) + ch] = acc[ch];
  __syncthreads();
  for (int i = 0; i < 16; ++i) {
    int lin = (i << 8) + tid;
    int cc = lin >> 5, pp2 = lin & 31;
    xs[(((long)(b << 7) + cc) << 14) + l0 + pp2] = fbf(xds[pp2 * 129 + cc]);
  }
  for (int task = tid; task < 320; task += 256) {
    int p2 = task / 10, r = task - p2 * 10;
    const float* wr = xpws + (r << 7);
    const float* xr = xds + p2 * 129;
    float sacc = 0.f;
#pragma unroll 8
    for (int cc = 0; cc < 128; ++cc) sacc = fmaf(wr[cc], xr[cc], sacc);
    xdbl[p2 * 12 + r] = sacc;
  }
  __syncthreads();
  for (int i = 0; i < 16; ++i) {
    int lin = (i << 8) + tid;
    int dd = lin >> 5, pp2 = lin & 31;
    const float* xb = xdbl + pp2 * 12;
    const float* wd = dtws + (dd << 3);
    float sacc = 0.f;
#pragma unroll
    for (int r = 0; r < 8; ++r) sacc = fmaf(wd[r], xb[r], sacc);
    dts[(((long)(b << 7) + dd) << 14) + l0 + pp2] = fbf(sacc);
  }
  if (tid < 32) {
    Bsb[((long)b << 14) + l0 + tid] = xdbl[tid * 12 + 8];
    Csb[((long)b << 14) + l0 + tid] = xdbl[tid * 12 + 9];
  }
}

// ---- K5: selective scan, shfl-based block scan, cheap softplus -------------
__global__ __launch_bounds__(1024) void k_scan(u16* __restrict__ xy,
                                               const u16* __restrict__ dts16,
                                               const float* __restrict__ Bsb,
                                               const float* __restrict__ Csb,
                                               const float* __restrict__ A_logs,
                                               const float* __restrict__ Dsv,
                                               const float* __restrict__ dtbv) {
  __shared__ float swp[16], swe[16];
  int bd = blockIdx.x;
  int b = bd >> 7, d = bd & 127;
  float Ad = -__expf(A_logs[d]);
  float dtb = dtbv[d];
  float Dd = Dsv[d];
  int t = threadIdx.x;
  int lane = t & 63, wid = t >> 6;
  long base = ((long)bd << 14) + (t << 4);
  long bb = ((long)b << 14) + (t << 4);
  const uint4* pz4 = (const uint4*)(dts16 + base);
  const uint4* px4 = (const uint4*)(xy + base);
  const float4* pB = (const float4*)(Bsb + bb);
  const float4* pC = (const float4*)(Csb + bb);
  uint4 zA = pz4[0], zB = pz4[1];
  uint4 xA = px4[0], xB = px4[1];
  u32 zw[8] = {zA.x, zA.y, zA.z, zA.w, zB.x, zB.y, zB.z, zB.w};
  u32 xw[8] = {xA.x, xA.y, xA.z, xA.w, xB.x, xB.y, xB.z, xB.w};
  float E = 0.f, P = 1.f;
#pragma unroll
  for (int q = 0; q < 4; ++q) {
    float4 B4 = pB[q];
    float Bq[4] = {B4.x, B4.y, B4.z, B4.w};
#pragma unroll
    for (int j = 0; j < 4; ++j) {
      int k = (q << 2) + j;
      float z = (k & 1) ? hi16(zw[k >> 1]) : lo16(zw[k >> 1]);
      float xv = (k & 1) ? hi16(xw[k >> 1]) : lo16(xw[k >> 1]);
      float delta = softplusf(z + dtb);
      float a = __expf(delta * Ad);
      E = fmaf(a, E, delta * Bq[j] * xv);
      P *= a;
    }
  }
#pragma unroll
  for (int off = 1; off < 64; off <<= 1) {
    float Pp = __shfl_up(P, off);
    float Ep = __shfl_up(E, off);
    if (lane >= off) { E = fmaf(P, Ep, E); P *= Pp; }
  }
  if (lane == 63) { swp[wid] = P; swe[wid] = E; }
  __syncthreads();
  if (t < 16) {
    float p2 = swp[t], e2 = swe[t];
#pragma unroll
    for (int off = 1; off < 16; off <<= 1) {
      float pp = __shfl_up(p2, off);
      float ee = __shfl_up(e2, off);
      if (t >= off) { e2 = fmaf(p2, ee, e2); p2 *= pp; }
    }
    swp[t] = p2; swe[t] = e2;
  }
  __syncthreads();
  float hw = (wid == 0) ? 0.f : swe[wid - 1];
  float Pex = __shfl_up(P, 1);
  float Eex = __shfl_up(E, 1);
  if (lane == 0) { Pex = 1.f; Eex = 0.f; }
  float h = fmaf(Pex, hw, Eex);
  u32 ypk[8];
#pragma unroll
  for (int q = 0; q < 4; ++q) {
    float4 B4 = pB[q];
    float4 C4 = pC[q];
    float Bq[4] = {B4.x, B4.y, B4.z, B4.w};
    float Cq[4] = {C4.x, C4.y, C4.z, C4.w};
#pragma unroll
    for (int j = 0; j < 4; ++j) {
      int k = (q << 2) + j;
      float z = (k & 1) ? hi16(zw[k >> 1]) : lo16(zw[k >> 1]);
      float xv = (k & 1) ? hi16(xw[k >> 1]) : lo16(xw[k >> 1]);
      float delta = softplusf(z + dtb);
      float a = __expf(delta * Ad);
      h = fmaf(a, h, delta * Bq[j] * xv);
      u16 yb = fbf(fmaf(Dd, xv, h * Cq[j]));
      if ((k & 1) == 0) ypk[k >> 1] = yb; else ypk[k >> 1] |= (u32)yb << 16;
    }
  }
  uint4* py = (uint4*)(xy + base);
  py[0] = make_uint4(ypk[0], ypk[1], ypk[2], ypk[3]);
  py[1] = make_uint4(ypk[4], ypk[5], ypk[6], ypk[7]);
}

// ---- K6b: s1[o]=sum W2*beta, s2[o]=sum W2*gamma ----------------------------
__global__ void k_sums(const float* __restrict__ W2, const float* __restrict__ g,
                       const float* __restrict__ bln, float* __restrict__ s12) {
  int o = threadIdx.x;
  float s1 = 0.f, s2 = 0.f;
  for (int c = 0; c < 128; ++c) {
    float w = W2[(o << 7) + c];
    s1 = fmaf(w, bln[c], s1);
    s2 = fmaf(w, g[c], s2);
  }
  s12[o] = s1;
  s12[128 + o] = s2;
}

// ---- K7: out_proj MFMA GEMM + fused LN epilogue (f32 out, [b,o,l]) ---------
__global__ __launch_bounds__(256) void k_outproj(const u16* __restrict__ y,
                                                 const float* __restrict__ W2,
                                                 const float* __restrict__ g,
                                                 const float* __restrict__ s12,
                                                 float* __restrict__ out) {
  __shared__ __align__(16) u16 Ws[128 * 136];  // [o][c] bf16 of W2*gamma
  __shared__ __align__(16) u16 Ys[64 * 136];   // [l][c] bf16 (y^T tile)
  __shared__ float ps[4][64], pss[4][64];
  __shared__ float mean_s[64], rstd_s[64];
  int tid = threadIdx.x;
  int b = blockIdx.x >> 8;
  int l0 = (blockIdx.x & 255) << 6;
  for (int i = 0; i < 16; ++i) {
    int idx = (i << 8) + tid;
    int o = idx >> 5, c4 = (idx & 31) << 2;
    float4 w4 = *(const float4*)&W2[(o << 7) + c4];
    ushort4 s;
    s.x = fbf(w4.x * g[c4]);     s.y = fbf(w4.y * g[c4 + 1]);
    s.z = fbf(w4.z * g[c4 + 2]); s.w = fbf(w4.w * g[c4 + 3]);
    *(ushort4*)&Ws[o * 136 + c4] = s;
  }
  for (int i = 0; i < 4; ++i) {
    int idx = (i << 8) + tid;
    int c = idx >> 3, lq = (idx & 7) << 3;
    uint4 v = *(const uint4*)&y[(((long)(b << 7) + c) << 14) + l0 + lq];
    u32 vv[4] = {v.x, v.y, v.z, v.w};
#pragma unroll
    for (int r = 0; r < 8; ++r)
      Ys[(lq + r) * 136 + c] = (u16)((r & 1) ? (vv[r >> 1] >> 16) : (vv[r >> 1] & 0xffffu));
  }
  __syncthreads();
  {  // per-l stats over c (4 partials per l)
    int l = tid & 63, q = tid >> 6;
    const u16* row = &Ys[l * 136 + (q << 5)];
    float s = 0.f, ss = 0.f;
#pragma unroll 8
    for (int c = 0; c < 32; ++c) { float v = bfu(row[c]); s += v; ss = fmaf(v, v, ss); }
    ps[q][l] = s; pss[q][l] = ss;
  }
  __syncthreads();
  if (tid < 64) {
    float s = ps[0][tid] + ps[1][tid] + ps[2][tid] + ps[3][tid];
    float ss = pss[0][tid] + pss[1][tid] + pss[2][tid] + pss[3][tid];
    float m = s * (1.f / 128.f);
    mean_s[tid] = m;
    rstd_s[tid] = rsqrtf(ss * (1.f / 128.f) - m * m + 1e-6f);
  }
  __syncthreads();
  int w = tid >> 6, lane = tid & 63;
  int mrow = lane & 15, quad = lane >> 4;
  f32x4 acc[2][4];
#pragma unroll
  for (int ot = 0; ot < 2; ++ot)
#pragma unroll
    for (int lt = 0; lt < 4; ++lt) acc[ot][lt] = (f32x4){0.f, 0.f, 0.f, 0.f};
#pragma unroll
  for (int kb = 0; kb < 4; ++kb) {
    int c0 = (kb << 5) + (quad << 3);
    bf16x8 af[2], bfr[4];
#pragma unroll
    for (int ot = 0; ot < 2; ++ot)
      af[ot] = ld_bf8(&Ws[((w << 5) + (ot << 4) + mrow) * 136 + c0]);
#pragma unroll
    for (int lt = 0; lt < 4; ++lt)
      bfr[lt] = ld_bf8(&Ys[((lt << 4) + mrow) * 136 + c0]);
#pragma unroll
    for (int ot = 0; ot < 2; ++ot)
#pragma unroll
      for (int lt = 0; lt < 4; ++lt)
        acc[ot][lt] = __builtin_amdgcn_mfma_f32_16x16x32_bf16(af[ot], bfr[lt], acc[ot][lt], 0, 0, 0);
  }
  float s1r[2][4], s2r[2][4];
#pragma unroll
  for (int ot = 0; ot < 2; ++ot)
#pragma unroll
    for (int r = 0; r < 4; ++r) {
      int o = (w << 5) + (ot << 4) + (quad << 2) + r;
      s1r[ot][r] = s12[o];
      s2r[ot][r] = s12[128 + o];
    }
#pragma unroll
  for (int ot = 0; ot < 2; ++ot)
#pragma unroll
    for (int lt = 0; lt < 4; ++lt) {
      int lcol = (lt << 4) + mrow;
      float mv = mean_s[lcol], rv = rstd_s[lcol];
      int obase = (w << 5) + (ot << 4) + (quad << 2);
#pragma unroll
      for (int r = 0; r < 4; ++r) {
        float v = fmaf(rv, acc[ot][lt][r] - mv * s2r[ot][r], s1r[ot][r]);
        out[(((long)(b << 7) + obase + r) << 14) + l0 + lcol] = v;
      }
    }
}

extern "C" void kernel_launch(void* const* d_in, const int* in_sizes, int n_in,
                              void* d_out, int out_size, void* d_ws, size_t ws_size,
                              hipStream_t stream) {
  const float* x         = (const float*)d_in[0];
  const float* in_proj_w = (const float*)d_in[1];
  const float* conv2d_w  = (const float*)d_in[2];
  const float* conv2d_b  = (const float*)d_in[3];
  const float* dw_w      = (const float*)d_in[4];
  const float* dw_b      = (const float*)d_in[5];
  const float* dw_ln_g   = (const float*)d_in[6];
  const float* dw_ln_b   = (const float*)d_in[7];
  const float* off_w     = (const float*)d_in[8];
  const float* off_b     = (const float*)d_in[9];
  const float* x_proj_w  = (const float*)d_in[10];
  const float* dt_w      = (const float*)d_in[11];
  const float* dt_b      = (const float*)d_in[12];
  const float* A_logs    = (const float*)d_in[13];
  const float* Ds        = (const float*)d_in[14];
  const float* out_ln_g  = (const float*)d_in[15];
  const float* out_ln_b  = (const float*)d_in[16];
  const float* out_proj_w= (const float*)d_in[17];
  float* out = (float*)d_out;

  u16* A  = (u16*)d_ws;            // xin_cl -> x1_cl -> xs[b,c,l] -> y[b,c,l]
  u16* Bx = A + 8388608;           // xc_cl
  u16* Dd = Bx + 8388608;          // dts[b,c,l]
  float* offs  = (float*)(Dd + 8388608);  // (B,L,16)
  float* Bsb   = offs + 1048576;
  float* Csb   = Bsb + 65536;
  float* s12   = Csb + 65536;

  hipLaunchKernelGGL(k_inproj, dim3(1024), dim3(256), 0, stream, x, in_proj_w, A);
  hipLaunchKernelGGL(k_dwconv, dim3(4096), dim3(256), 0, stream, A, conv2d_w, conv2d_b, Bx, 1);
  hipLaunchKernelGGL(k_dwconv, dim3(4096), dim3(256), 0, stream, Bx, dw_w, dw_b, A, 0);
  hipLaunchKernelGGL(k_offset, dim3(256), dim3(256), 0, stream, A, dw_ln_g, dw_ln_b, off_w, off_b, offs);
  hipLaunchKernelGGL(k_dcn, dim3(2048), dim3(256), 0, stream, Bx, offs, x_proj_w, dt_w, A, Dd, Bsb, Csb);
  hipLaunchKernelGGL(k_scan, dim3(512), dim3(1024), 0, stream, A, Dd, Bsb, Csb, A_logs, Ds, dt_b);
  hipLaunchKernelGGL(k_sums, dim3(1), dim3(128), 0, stream, out_proj_w, out_ln_g, out_ln_b, s12);
  hipLaunchKernelGGL(k_outproj, dim3(1024), dim3(256), 0, stream, A, out_proj_w, out_ln_g, s12, out);
}

// Round 7
// 246.674 us; speedup vs baseline: 1.8527x; 1.0102x over previous
//
#include <hip/hip_runtime.h>
#include <hip/hip_bf16.h>

typedef unsigned short u16;
typedef unsigned int u32;
typedef __bf16 bf16x8 __attribute__((ext_vector_type(8)));
typedef float f32x4 __attribute__((ext_vector_type(4)));

__device__ __forceinline__ float bfu(u16 u) { return __uint_as_float(((u32)u) << 16); }
__device__ __forceinline__ u16 fbf(float f) {
  __hip_bfloat16 h = __float2bfloat16(f);
  return *reinterpret_cast<u16*>(&h);
}
__device__ __forceinline__ float softplusf(float z) {
  float t = __expf(z);
  return (z > 20.f) ? z : __logf(1.f + t);
}
__device__ __forceinline__ float lo16(u32 p) { return __uint_as_float(p << 16); }
__device__ __forceinline__ float hi16(u32 p) { return __uint_as_float(p & 0xffff0000u); }
__device__ __forceinline__ bf16x8 ld_bf8(const u16* p) {
  union { uint4 u; bf16x8 v; } c;
  c.u = *(const uint4*)p;
  return c.v;
}

// ---- K1: in_proj MFMA GEMM: out_cl[b,l,o] = sum_c W[o,c] * X[b,c,l] --------
__global__ __launch_bounds__(256) void k_inproj(const float* __restrict__ X,
                                                const float* __restrict__ W,
                                                u16* __restrict__ out) {
  __shared__ __align__(16) u16 Ws[128 * 136];  // [o][c] bf16
  __shared__ __align__(16) u16 Xs[64 * 136];   // [l][c] bf16 (X^T tile)
  int tid = threadIdx.x;
  int b = blockIdx.x >> 8;
  int l0 = (blockIdx.x & 255) << 6;
  for (int i = 0; i < 16; ++i) {
    int idx = (i << 8) + tid;
    int o = idx >> 5, c4 = (idx & 31) << 2;
    float4 w4 = *(const float4*)&W[(o << 7) + c4];
    ushort4 s;
    s.x = fbf(w4.x); s.y = fbf(w4.y); s.z = fbf(w4.z); s.w = fbf(w4.w);
    *(ushort4*)&Ws[o * 136 + c4] = s;
  }
  for (int i = 0; i < 8; ++i) {
    int idx = (i << 8) + tid;
    int c = idx >> 4, lq = (idx & 15) << 2;
    float4 x4 = *(const float4*)&X[(((long)(b << 7) + c) << 14) + l0 + lq];
    Xs[(lq + 0) * 136 + c] = fbf(x4.x);
    Xs[(lq + 1) * 136 + c] = fbf(x4.y);
    Xs[(lq + 2) * 136 + c] = fbf(x4.z);
    Xs[(lq + 3) * 136 + c] = fbf(x4.w);
  }
  __syncthreads();
  int w = tid >> 6, lane = tid & 63;
  int mrow = lane & 15, quad = lane >> 4;
  f32x4 acc[2][4];
#pragma unroll
  for (int ot = 0; ot < 2; ++ot)
#pragma unroll
    for (int lt = 0; lt < 4; ++lt) acc[ot][lt] = (f32x4){0.f, 0.f, 0.f, 0.f};
#pragma unroll
  for (int kb = 0; kb < 4; ++kb) {
    int c0 = (kb << 5) + (quad << 3);
    bf16x8 af[2], bfr[4];
#pragma unroll
    for (int ot = 0; ot < 2; ++ot)
      af[ot] = ld_bf8(&Ws[((w << 5) + (ot << 4) + mrow) * 136 + c0]);
#pragma unroll
    for (int lt = 0; lt < 4; ++lt)
      bfr[lt] = ld_bf8(&Xs[((lt << 4) + mrow) * 136 + c0]);
#pragma unroll
    for (int ot = 0; ot < 2; ++ot)
#pragma unroll
      for (int lt = 0; lt < 4; ++lt)
        acc[ot][lt] = __builtin_amdgcn_mfma_f32_16x16x32_bf16(af[ot], bfr[lt], acc[ot][lt], 0, 0, 0);
  }
#pragma unroll
  for (int ot = 0; ot < 2; ++ot)
#pragma unroll
    for (int lt = 0; lt < 4; ++lt) {
      int l = l0 + (lt << 4) + mrow;
      int o = (w << 5) + (ot << 4) + (quad << 2);
      ushort4 s;
      s.x = fbf(acc[ot][lt][0]); s.y = fbf(acc[ot][lt][1]);
      s.z = fbf(acc[ot][lt][2]); s.w = fbf(acc[ot][lt][3]);
      *(ushort4*)&out[(((long)(b << 14) + l) << 7) + o] = s;
    }
}

// ---- K2/K3a: depthwise 3x3 conv, channels-last, optional SiLU --------------
__global__ __launch_bounds__(256) void k_dwconv(const u16* __restrict__ in,
                                                const float* __restrict__ w9,
                                                const float* __restrict__ bias,
                                                u16* __restrict__ out, int act) {
  __shared__ float wsT[9][128];
  __shared__ float bs[128];
  int tid = threadIdx.x;
  for (int i = 0; i < 5; ++i) {
    int lin = (i << 8) + tid;
    if (lin < 1152) { int c = lin / 9, k = lin - 9 * c; wsT[k][c] = w9[lin]; }
  }
  if (tid < 128) bs[tid] = bias[tid];
  __syncthreads();
  int blk = blockIdx.x;
  int b = blk >> 10;
  int s = blk & 1023;
  int h = s >> 3;
  int w = ((s & 7) << 4) + (tid >> 4);
  int c0 = (tid & 15) << 3;
  const u16* bbase = in + ((long)b << 21);
  float acc[8];
  {
    float4 b0 = *(const float4*)&bs[c0];
    float4 b1 = *(const float4*)&bs[c0 + 4];
    acc[0] = b0.x; acc[1] = b0.y; acc[2] = b0.z; acc[3] = b0.w;
    acc[4] = b1.x; acc[5] = b1.y; acc[6] = b1.z; acc[7] = b1.w;
  }
#pragma unroll
  for (int ky = -1; ky <= 1; ++ky) {
    int y = h + ky;
    if ((unsigned)y >= 128u) continue;
#pragma unroll
    for (int kx = -1; kx <= 1; ++kx) {
      int x = w + kx;
      if ((unsigned)x >= 128u) continue;
      int k = (ky + 1) * 3 + (kx + 1);
      uint4 v = *(const uint4*)(bbase + ((((y << 7) + x)) << 7) + c0);
      float4 w0 = *(const float4*)&wsT[k][c0];
      float4 w1 = *(const float4*)&wsT[k][c0 + 4];
      u32 vv[4] = {v.x, v.y, v.z, v.w};
      float wf[8] = {w0.x, w0.y, w0.z, w0.w, w1.x, w1.y, w1.z, w1.w};
#pragma unroll
      for (int cc = 0; cc < 8; ++cc) {
        float xv = (cc & 1) ? hi16(vv[cc >> 1]) : lo16(vv[cc >> 1]);
        acc[cc] = fmaf(wf[cc], xv, acc[cc]);
      }
    }
  }
  if (act) {
#pragma unroll
    for (int cc = 0; cc < 8; ++cc) acc[cc] = acc[cc] / (1.f + __expf(-acc[cc]));
  }
  ushort4 s0, s1;
  s0.x = fbf(acc[0]); s0.y = fbf(acc[1]); s0.z = fbf(acc[2]); s0.w = fbf(acc[3]);
  s1.x = fbf(acc[4]); s1.y = fbf(acc[5]); s1.z = fbf(acc[6]); s1.w = fbf(acc[7]);
  u16* po = out + ((long)b << 21) + ((((h << 7) + w)) << 7) + c0;
  *(ushort4*)po = s0;
  *(ushort4*)(po + 4) = s1;
}

// ---- K3b: per-pixel LN + GELU + offset proj; offs layout [b][g][l] float2 --
__global__ __launch_bounds__(256) void k_offset(const u16* __restrict__ x1,
                                                const float* __restrict__ g,
                                                const float* __restrict__ bt,
                                                const float* __restrict__ offw,
                                                const float* __restrict__ offb,
                                                float* __restrict__ offs) {
  __shared__ float Wo[16 * 128];
  __shared__ float gs[128], bsh[128];
  int tid = threadIdx.x;
  if (tid < 128) { gs[tid] = g[tid]; bsh[tid] = bt[tid]; }
  for (int i = 0; i < 8; ++i) { int idx = (i << 8) + tid; Wo[idx] = offw[idx]; }
  __syncthreads();
  int pg = (blockIdx.x << 8) + tid;  // b*L + l
  int b = pg >> 14, l = pg & 16383;
  const uint4* px = (const uint4*)(x1 + ((long)pg << 7));
  float s = 0.f, ss = 0.f;
  for (int i = 0; i < 16; ++i) {
    uint4 v = px[i];
    u32 vv[4] = {v.x, v.y, v.z, v.w};
#pragma unroll
    for (int cc = 0; cc < 8; ++cc) {
      float xv = (cc & 1) ? hi16(vv[cc >> 1]) : lo16(vv[cc >> 1]);
      s += xv; ss = fmaf(xv, xv, ss);
    }
  }
  float mean = s * (1.f / 128.f);
  float var = ss * (1.f / 128.f) - mean * mean;
  float rstd = rsqrtf(var + 1e-6f);
  float acc[16];
#pragma unroll
  for (int j = 0; j < 16; ++j) acc[j] = offb[j];
  for (int i = 0; i < 16; ++i) {
    uint4 v = px[i];  // L1 hit
    u32 vv[4] = {v.x, v.y, v.z, v.w};
#pragma unroll
    for (int cc = 0; cc < 8; ++cc) {
      int c = (i << 3) + cc;
      float xv = (cc & 1) ? hi16(vv[cc >> 1]) : lo16(vv[cc >> 1]);
      float xn = fmaf((xv - mean) * rstd, gs[c], bsh[c]);
      float ge = 0.5f * xn * (1.f + erff(xn * 0.70710678118f));
#pragma unroll
      for (int j = 0; j < 16; ++j) acc[j] = fmaf(Wo[j * 128 + c], ge, acc[j]);
    }
  }
  float2* po = (float2*)offs;
#pragma unroll
  for (int gg = 0; gg < 8; ++gg)
    po[(((long)((b << 3) + gg)) << 14) + l] = make_float2(acc[2 * gg], acc[2 * gg + 1]);
}

// ---- K4: DCN bilinear gather + x_proj + dt_w fused; p=tid&31, gg=tid>>5 ----
__global__ __launch_bounds__(256) void k_dcn(const u16* __restrict__ xc,
                                             const float* __restrict__ offs,
                                             const float* __restrict__ xpw,
                                             const float* __restrict__ dtw,
                                             u16* __restrict__ xs,
                                             u16* __restrict__ dts,
                                             float* __restrict__ Bsb,
                                             float* __restrict__ Csb) {
  __shared__ float xds[32 * 129];   // [p][c], stride 129 -> 2-way alias (free)
  __shared__ float xdbl[32 * 13];   // [p][r], stride 13 -> conflict-free reads
  __shared__ float xpws[1280];
  __shared__ float dtws[1024];
  int tid = threadIdx.x;
  for (int i = 0; i < 5; ++i) { int idx = (i << 8) + tid; if (idx < 1280) xpws[idx] = xpw[idx]; }
  for (int i = 0; i < 4; ++i) { int idx = (i << 8) + tid; dtws[idx] = dtw[idx]; }
  int blk = blockIdx.x;
  int b = blk >> 9;
  int l0 = (blk & 511) << 5;
  int p = tid & 31, gg = tid >> 5;
  int l = l0 + p, hh = l >> 7, ww = l & 127;
  float2 off = ((const float2*)offs)[(((long)((b << 3) + gg)) << 14) + l];
  float px = (float)ww + off.x, py = (float)hh + off.y;
  float x0f = floorf(px), y0f = floorf(py);
  float wx = px - x0f, wy = py - y0f;
  int ix = (int)x0f, iy = (int)y0f;
  float acc[16];
#pragma unroll
  for (int ch = 0; ch < 16; ++ch) acc[ch] = 0.f;
  const u16* bbase = xc + ((long)b << 21) + (gg << 4);
  int xi[4] = {ix, ix + 1, ix, ix + 1};
  int yi[4] = {iy, iy, iy + 1, iy + 1};
  float wt4[4] = {(1.f - wy) * (1.f - wx), (1.f - wy) * wx, wy * (1.f - wx), wy * wx};
#pragma unroll
  for (int t = 0; t < 4; ++t) {
    if (wt4[t] != 0.f && (unsigned)yi[t] < 128u && (unsigned)xi[t] < 128u) {
      const u16* pp = bbase + ((((yi[t] << 7) + xi[t])) << 7);
      uint4 v0 = *(const uint4*)pp;
      uint4 v1 = *(const uint4*)(pp + 8);
      float wv = wt4[t];
      u32 vv[8] = {v0.x, v0.y, v0.z, v0.w, v1.x, v1.y, v1.z, v1.w};
#pragma unroll
      for (int ch = 0; ch < 16; ++ch) {
        float xv = (ch & 1) ? hi16(vv[ch >> 1]) : lo16(vv[ch >> 1]);
        acc[ch] = fmaf(wv, xv, acc[ch]);
      }
    }
  }
#pragma unroll
  for (int ch = 0; ch < 16; ++ch) xds[p * 129 + (gg << 4) + ch] = acc[ch];
  __syncthreads();
  // xs store: lane-task = (row cc, l-quad t); LDS banks 2-way (free); 8B stores
  for (int it = 0; it < 4; ++it) {
    int task = (it << 8) + tid;
    int cc = task >> 3, t = task & 7;
    ushort4 s;
    s.x = fbf(xds[(4 * t + 0) * 129 + cc]);
    s.y = fbf(xds[(4 * t + 1) * 129 + cc]);
    s.z = fbf(xds[(4 * t + 2) * 129 + cc]);
    s.w = fbf(xds[(4 * t + 3) * 129 + cc]);
    *(ushort4*)&xs[(((long)(b << 7) + cc) << 14) + l0 + (t << 2)] = s;
  }
  for (int task = tid; task < 320; task += 256) {
    int p2 = task / 10, r = task - p2 * 10;
    const float* wr = xpws + (r << 7);
    const float* xr = xds + p2 * 129;
    float sacc = 0.f;
#pragma unroll 8
    for (int cc = 0; cc < 128; ++cc) sacc = fmaf(wr[cc], xr[cc], sacc);
    xdbl[p2 * 13 + r] = sacc;
  }
  __syncthreads();
  // dts: lane-task = (row dd, l-quad t); xdbl stride 13 -> conflict-free
  for (int it = 0; it < 4; ++it) {
    int task = (it << 8) + tid;
    int dd = task >> 3, t = task & 7;
    const float* wd = dtws + (dd << 3);
    u16 sv[4];
#pragma unroll
    for (int j = 0; j < 4; ++j) {
      const float* xb = xdbl + (4 * t + j) * 13;
      float sacc = 0.f;
#pragma unroll
      for (int r = 0; r < 8; ++r) sacc = fmaf(wd[r], xb[r], sacc);
      sv[j] = fbf(sacc);
    }
    ushort4 s; s.x = sv[0]; s.y = sv[1]; s.z = sv[2]; s.w = sv[3];
    *(ushort4*)&dts[(((long)(b << 7) + dd) << 14) + l0 + (t << 2)] = s;
  }
  if (tid < 32) {
    Bsb[((long)b << 14) + l0 + tid] = xdbl[tid * 13 + 8];
    Csb[((long)b << 14) + l0 + tid] = xdbl[tid * 13 + 9];
  }
}

// ---- K5: selective scan, shfl-based block scan, cheap softplus -------------
__global__ __launch_bounds__(1024) void k_scan(u16* __restrict__ xy,
                                               const u16* __restrict__ dts16,
                                               const float* __restrict__ Bsb,
                                               const float* __restrict__ Csb,
                                               const float* __restrict__ A_logs,
                                               const float* __restrict__ Dsv,
                                               const float* __restrict__ dtbv) {
  __shared__ float swp[16], swe[16];
  int bd = blockIdx.x;
  int b = bd >> 7, d = bd & 127;
  float Ad = -__expf(A_logs[d]);
  float dtb = dtbv[d];
  float Dd = Dsv[d];
  int t = threadIdx.x;
  int lane = t & 63, wid = t >> 6;
  long base = ((long)bd << 14) + (t << 4);
  long bb = ((long)b << 14) + (t << 4);
  const uint4* pz4 = (const uint4*)(dts16 + base);
  const uint4* px4 = (const uint4*)(xy + base);
  const float4* pB = (const float4*)(Bsb + bb);
  const float4* pC = (const float4*)(Csb + bb);
  uint4 zA = pz4[0], zB = pz4[1];
  uint4 xA = px4[0], xB = px4[1];
  u32 zw[8] = {zA.x, zA.y, zA.z, zA.w, zB.x, zB.y, zB.z, zB.w};
  u32 xw[8] = {xA.x, xA.y, xA.z, xA.w, xB.x, xB.y, xB.z, xB.w};
  float E = 0.f, P = 1.f;
#pragma unroll
  for (int q = 0; q < 4; ++q) {
    float4 B4 = pB[q];
    float Bq[4] = {B4.x, B4.y, B4.z, B4.w};
#pragma unroll
    for (int j = 0; j < 4; ++j) {
      int k = (q << 2) + j;
      float z = (k & 1) ? hi16(zw[k >> 1]) : lo16(zw[k >> 1]);
      float xv = (k & 1) ? hi16(xw[k >> 1]) : lo16(xw[k >> 1]);
      float delta = softplusf(z + dtb);
      float a = __expf(delta * Ad);
      E = fmaf(a, E, delta * Bq[j] * xv);
      P *= a;
    }
  }
#pragma unroll
  for (int off = 1; off < 64; off <<= 1) {
    float Pp = __shfl_up(P, off);
    float Ep = __shfl_up(E, off);
    if (lane >= off) { E = fmaf(P, Ep, E); P *= Pp; }
  }
  if (lane == 63) { swp[wid] = P; swe[wid] = E; }
  __syncthreads();
  if (t < 16) {
    float p2 = swp[t], e2 = swe[t];
#pragma unroll
    for (int off = 1; off < 16; off <<= 1) {
      float pp = __shfl_up(p2, off);
      float ee = __shfl_up(e2, off);
      if (t >= off) { e2 = fmaf(p2, ee, e2); p2 *= pp; }
    }
    swp[t] = p2; swe[t] = e2;
  }
  __syncthreads();
  float hw = (wid == 0) ? 0.f : swe[wid - 1];
  float Pex = __shfl_up(P, 1);
  float Eex = __shfl_up(E, 1);
  if (lane == 0) { Pex = 1.f; Eex = 0.f; }
  float h = fmaf(Pex, hw, Eex);
  u32 ypk[8];
#pragma unroll
  for (int q = 0; q < 4; ++q) {
    float4 B4 = pB[q];
    float4 C4 = pC[q];
    float Bq[4] = {B4.x, B4.y, B4.z, B4.w};
    float Cq[4] = {C4.x, C4.y, C4.z, C4.w};
#pragma unroll
    for (int j = 0; j < 4; ++j) {
      int k = (q << 2) + j;
      float z = (k & 1) ? hi16(zw[k >> 1]) : lo16(zw[k >> 1]);
      float xv = (k & 1) ? hi16(xw[k >> 1]) : lo16(xw[k >> 1]);
      float delta = softplusf(z + dtb);
      float a = __expf(delta * Ad);
      h = fmaf(a, h, delta * Bq[j] * xv);
      u16 yb = fbf(fmaf(Dd, xv, h * Cq[j]));
      if ((k & 1) == 0) ypk[k >> 1] = yb; else ypk[k >> 1] |= (u32)yb << 16;
    }
  }
  uint4* py = (uint4*)(xy + base);
  py[0] = make_uint4(ypk[0], ypk[1], ypk[2], ypk[3]);
  py[1] = make_uint4(ypk[4], ypk[5], ypk[6], ypk[7]);
}

// ---- K6b: s1[o]=sum W2*beta, s2[o]=sum W2*gamma ----------------------------
__global__ void k_sums(const float* __restrict__ W2, const float* __restrict__ g,
                       const float* __restrict__ bln, float* __restrict__ s12) {
  int o = threadIdx.x;
  float s1 = 0.f, s2 = 0.f;
  for (int c = 0; c < 128; ++c) {
    float w = W2[(o << 7) + c];
    s1 = fmaf(w, bln[c], s1);
    s2 = fmaf(w, g[c], s2);
  }
  s12[o] = s1;
  s12[128 + o] = s2;
}

// ---- K7: out_proj MFMA GEMM + fused LN epilogue (f32 out, [b,o,l]) ---------
__global__ __launch_bounds__(256) void k_outproj(const u16* __restrict__ y,
                                                 const float* __restrict__ W2,
                                                 const float* __restrict__ g,
                                                 const float* __restrict__ s12,
                                                 float* __restrict__ out) {
  __shared__ __align__(16) u16 Ws[128 * 136];  // [o][c] bf16 of W2*gamma
  __shared__ __align__(16) u16 Ys[64 * 136];   // [l][c] bf16 (y^T tile)
  __shared__ float ps[4][64], pss[4][64];
  __shared__ float mean_s[64], rstd_s[64];
  int tid = threadIdx.x;
  int b = blockIdx.x >> 8;
  int l0 = (blockIdx.x & 255) << 6;
  for (int i = 0; i < 16; ++i) {
    int idx = (i << 8) + tid;
    int o = idx >> 5, c4 = (idx & 31) << 2;
    float4 w4 = *(const float4*)&W2[(o << 7) + c4];
    ushort4 s;
    s.x = fbf(w4.x * g[c4]);     s.y = fbf(w4.y * g[c4 + 1]);
    s.z = fbf(w4.z * g[c4 + 2]); s.w = fbf(w4.w * g[c4 + 3]);
    *(ushort4*)&Ws[o * 136 + c4] = s;
  }
  for (int i = 0; i < 4; ++i) {
    int idx = (i << 8) + tid;
    int c = idx >> 3, lq = (idx & 7) << 3;
    uint4 v = *(const uint4*)&y[(((long)(b << 7) + c) << 14) + l0 + lq];
    u32 vv[4] = {v.x, v.y, v.z, v.w};
#pragma unroll
    for (int r = 0; r < 8; ++r)
      Ys[(lq + r) * 136 + c] = (u16)((r & 1) ? (vv[r >> 1] >> 16) : (vv[r >> 1] & 0xffffu));
  }
  __syncthreads();
  {
    int l = tid & 63, q = tid >> 6;
    const u16* row = &Ys[l * 136 + (q << 5)];
    float s = 0.f, ss = 0.f;
#pragma unroll 8
    for (int c = 0; c < 32; ++c) { float v = bfu(row[c]); s += v; ss = fmaf(v, v, ss); }
    ps[q][l] = s; pss[q][l] = ss;
  }
  __syncthreads();
  if (tid < 64) {
    float s = ps[0][tid] + ps[1][tid] + ps[2][tid] + ps[3][tid];
    float ss = pss[0][tid] + pss[1][tid] + pss[2][tid] + pss[3][tid];
    float m = s * (1.f / 128.f);
    mean_s[tid] = m;
    rstd_s[tid] = rsqrtf(ss * (1.f / 128.f) - m * m + 1e-6f);
  }
  __syncthreads();
  int w = tid >> 6, lane = tid & 63;
  int mrow = lane & 15, quad = lane >> 4;
  f32x4 acc[2][4];
#pragma unroll
  for (int ot = 0; ot < 2; ++ot)
#pragma unroll
    for (int lt = 0; lt < 4; ++lt) acc[ot][lt] = (f32x4){0.f, 0.f, 0.f, 0.f};
#pragma unroll
  for (int kb = 0; kb < 4; ++kb) {
    int c0 = (kb << 5) + (quad << 3);
    bf16x8 af[2], bfr[4];
#pragma unroll
    for (int ot = 0; ot < 2; ++ot)
      af[ot] = ld_bf8(&Ws[((w << 5) + (ot << 4) + mrow) * 136 + c0]);
#pragma unroll
    for (int lt = 0; lt < 4; ++lt)
      bfr[lt] = ld_bf8(&Ys[((lt << 4) + mrow) * 136 + c0]);
#pragma unroll
    for (int ot = 0; ot < 2; ++ot)
#pragma unroll
      for (int lt = 0; lt < 4; ++lt)
        acc[ot][lt] = __builtin_amdgcn_mfma_f32_16x16x32_bf16(af[ot], bfr[lt], acc[ot][lt], 0, 0, 0);
  }
  float s1r[2][4], s2r[2][4];
#pragma unroll
  for (int ot = 0; ot < 2; ++ot)
#pragma unroll
    for (int r = 0; r < 4; ++r) {
      int o = (w << 5) + (ot << 4) + (quad << 2) + r;
      s1r[ot][r] = s12[o];
      s2r[ot][r] = s12[128 + o];
    }
#pragma unroll
  for (int ot = 0; ot < 2; ++ot)
#pragma unroll
    for (int lt = 0; lt < 4; ++lt) {
      int lcol = (lt << 4) + mrow;
      float mv = mean_s[lcol], rv = rstd_s[lcol];
      int obase = (w << 5) + (ot << 4) + (quad << 2);
#pragma unroll
      for (int r = 0; r < 4; ++r) {
        float v = fmaf(rv, acc[ot][lt][r] - mv * s2r[ot][r], s1r[ot][r]);
        out[(((long)(b << 7) + obase + r) << 14) + l0 + lcol] = v;
      }
    }
}

extern "C" void kernel_launch(void* const* d_in, const int* in_sizes, int n_in,
                              void* d_out, int out_size, void* d_ws, size_t ws_size,
                              hipStream_t stream) {
  const float* x         = (const float*)d_in[0];
  const float* in_proj_w = (const float*)d_in[1];
  const float* conv2d_w  = (const float*)d_in[2];
  const float* conv2d_b  = (const float*)d_in[3];
  const float* dw_w      = (const float*)d_in[4];
  const float* dw_b      = (const float*)d_in[5];
  const float* dw_ln_g   = (const float*)d_in[6];
  const float* dw_ln_b   = (const float*)d_in[7];
  const float* off_w     = (const float*)d_in[8];
  const float* off_b     = (const float*)d_in[9];
  const float* x_proj_w  = (const float*)d_in[10];
  const float* dt_w      = (const float*)d_in[11];
  const float* dt_b      = (const float*)d_in[12];
  const float* A_logs    = (const float*)d_in[13];
  const float* Ds        = (const float*)d_in[14];
  const float* out_ln_g  = (const float*)d_in[15];
  const float* out_ln_b  = (const float*)d_in[16];
  const float* out_proj_w= (const float*)d_in[17];
  float* out = (float*)d_out;

  u16* A  = (u16*)d_ws;            // xin_cl -> x1_cl -> xs[b,c,l] -> y[b,c,l]
  u16* Bx = A + 8388608;           // xc_cl
  u16* Dd = Bx + 8388608;          // dts[b,c,l]
  float* offs  = (float*)(Dd + 8388608);  // [b][g][l] float2
  float* Bsb   = offs + 1048576;
  float* Csb   = Bsb + 65536;
  float* s12   = Csb + 65536;

  hipLaunchKernelGGL(k_inproj, dim3(1024), dim3(256), 0, stream, x, in_proj_w, A);
  hipLaunchKernelGGL(k_dwconv, dim3(4096), dim3(256), 0, stream, A, conv2d_w, conv2d_b, Bx, 1);
  hipLaunchKernelGGL(k_dwconv, dim3(4096), dim3(256), 0, stream, Bx, dw_w, dw_b, A, 0);
  hipLaunchKernelGGL(k_offset, dim3(256), dim3(256), 0, stream, A, dw_ln_g, dw_ln_b, off_w, off_b, offs);
  hipLaunchKernelGGL(k_dcn, dim3(2048), dim3(256), 0, stream, Bx, offs, x_proj_w, dt_w, A, Dd, Bsb, Csb);
  hipLaunchKernelGGL(k_scan, dim3(512), dim3(1024), 0, stream, A, Dd, Bsb, Csb, A_logs, Ds, dt_b);
  hipLaunchKernelGGL(k_sums, dim3(1), dim3(128), 0, stream, out_proj_w, out_ln_g, out_ln_b, s12);
  hipLaunchKernelGGL(k_outproj, dim3(1024), dim3(256), 0, stream, A, out_proj_w, out_ln_g, s12, out);
}

// Round 8
// 235.678 us; speedup vs baseline: 1.9392x; 1.0467x over previous
//
#include <hip/hip_runtime.h>
#include <hip/hip_bf16.h>

typedef unsigned short u16;
typedef unsigned int u32;
typedef __bf16 bf16x8 __attribute__((ext_vector_type(8)));
typedef float f32x4 __attribute__((ext_vector_type(4)));

__device__ __forceinline__ float bfu(u16 u) { return __uint_as_float(((u32)u) << 16); }
__device__ __forceinline__ u16 fbf(float f) {
  __hip_bfloat16 h = __float2bfloat16(f);
  return *reinterpret_cast<u16*>(&h);
}
__device__ __forceinline__ float softplusf(float z) {
  float t = __expf(z);
  return (z > 20.f) ? z : __logf(1.f + t);
}
__device__ __forceinline__ float lo16(u32 p) { return __uint_as_float(p << 16); }
__device__ __forceinline__ float hi16(u32 p) { return __uint_as_float(p & 0xffff0000u); }
__device__ __forceinline__ bf16x8 ld_bf8(const u16* p) {
  union { uint4 u; bf16x8 v; } c;
  c.u = *(const uint4*)p;
  return c.v;
}

// ---- K1: in_proj MFMA GEMM: out_cl[b,l,o] = sum_c W[o,c] * X[b,c,l] --------
__global__ __launch_bounds__(256) void k_inproj(const float* __restrict__ X,
                                                const float* __restrict__ W,
                                                u16* __restrict__ out) {
  __shared__ __align__(16) u16 Ws[128 * 136];  // [o][c] bf16
  __shared__ __align__(16) u16 Xs[64 * 136];   // [l][c] bf16 (X^T tile)
  int tid = threadIdx.x;
  int b = blockIdx.x >> 8;
  int l0 = (blockIdx.x & 255) << 6;
  for (int i = 0; i < 16; ++i) {
    int idx = (i << 8) + tid;
    int o = idx >> 5, c4 = (idx & 31) << 2;
    float4 w4 = *(const float4*)&W[(o << 7) + c4];
    ushort4 s;
    s.x = fbf(w4.x); s.y = fbf(w4.y); s.z = fbf(w4.z); s.w = fbf(w4.w);
    *(ushort4*)&Ws[o * 136 + c4] = s;
  }
  for (int i = 0; i < 8; ++i) {
    int idx = (i << 8) + tid;
    int c = idx >> 4, lq = (idx & 15) << 2;
    float4 x4 = *(const float4*)&X[(((long)(b << 7) + c) << 14) + l0 + lq];
    Xs[(lq + 0) * 136 + c] = fbf(x4.x);
    Xs[(lq + 1) * 136 + c] = fbf(x4.y);
    Xs[(lq + 2) * 136 + c] = fbf(x4.z);
    Xs[(lq + 3) * 136 + c] = fbf(x4.w);
  }
  __syncthreads();
  int w = tid >> 6, lane = tid & 63;
  int mrow = lane & 15, quad = lane >> 4;
  f32x4 acc[2][4];
#pragma unroll
  for (int ot = 0; ot < 2; ++ot)
#pragma unroll
    for (int lt = 0; lt < 4; ++lt) acc[ot][lt] = (f32x4){0.f, 0.f, 0.f, 0.f};
#pragma unroll
  for (int kb = 0; kb < 4; ++kb) {
    int c0 = (kb << 5) + (quad << 3);
    bf16x8 af[2], bfr[4];
#pragma unroll
    for (int ot = 0; ot < 2; ++ot)
      af[ot] = ld_bf8(&Ws[((w << 5) + (ot << 4) + mrow) * 136 + c0]);
#pragma unroll
    for (int lt = 0; lt < 4; ++lt)
      bfr[lt] = ld_bf8(&Xs[((lt << 4) + mrow) * 136 + c0]);
#pragma unroll
    for (int ot = 0; ot < 2; ++ot)
#pragma unroll
      for (int lt = 0; lt < 4; ++lt)
        acc[ot][lt] = __builtin_amdgcn_mfma_f32_16x16x32_bf16(af[ot], bfr[lt], acc[ot][lt], 0, 0, 0);
  }
#pragma unroll
  for (int ot = 0; ot < 2; ++ot)
#pragma unroll
    for (int lt = 0; lt < 4; ++lt) {
      int l = l0 + (lt << 4) + mrow;
      int o = (w << 5) + (ot << 4) + (quad << 2);
      ushort4 s;
      s.x = fbf(acc[ot][lt][0]); s.y = fbf(acc[ot][lt][1]);
      s.z = fbf(acc[ot][lt][2]); s.w = fbf(acc[ot][lt][3]);
      *(ushort4*)&out[(((long)(b << 14) + l) << 7) + o] = s;
    }
}

// ---- K2/K3a: depthwise 3x3 conv, channels-last, optional SiLU --------------
__global__ __launch_bounds__(256) void k_dwconv(const u16* __restrict__ in,
                                                const float* __restrict__ w9,
                                                const float* __restrict__ bias,
                                                u16* __restrict__ out, int act) {
  __shared__ float wsT[9][128];
  __shared__ float bs[128];
  int tid = threadIdx.x;
  for (int i = 0; i < 5; ++i) {
    int lin = (i << 8) + tid;
    if (lin < 1152) { int c = lin / 9, k = lin - 9 * c; wsT[k][c] = w9[lin]; }
  }
  if (tid < 128) bs[tid] = bias[tid];
  __syncthreads();
  int blk = blockIdx.x;
  int b = blk >> 10;
  int s = blk & 1023;
  int h = s >> 3;
  int w = ((s & 7) << 4) + (tid >> 4);
  int c0 = (tid & 15) << 3;
  const u16* bbase = in + ((long)b << 21);
  float acc[8];
  {
    float4 b0 = *(const float4*)&bs[c0];
    float4 b1 = *(const float4*)&bs[c0 + 4];
    acc[0] = b0.x; acc[1] = b0.y; acc[2] = b0.z; acc[3] = b0.w;
    acc[4] = b1.x; acc[5] = b1.y; acc[6] = b1.z; acc[7] = b1.w;
  }
#pragma unroll
  for (int ky = -1; ky <= 1; ++ky) {
    int y = h + ky;
    if ((unsigned)y >= 128u) continue;
#pragma unroll
    for (int kx = -1; kx <= 1; ++kx) {
      int x = w + kx;
      if ((unsigned)x >= 128u) continue;
      int k = (ky + 1) * 3 + (kx + 1);
      uint4 v = *(const uint4*)(bbase + ((((y << 7) + x)) << 7) + c0);
      float4 w0 = *(const float4*)&wsT[k][c0];
      float4 w1 = *(const float4*)&wsT[k][c0 + 4];
      u32 vv[4] = {v.x, v.y, v.z, v.w};
      float wf[8] = {w0.x, w0.y, w0.z, w0.w, w1.x, w1.y, w1.z, w1.w};
#pragma unroll
      for (int cc = 0; cc < 8; ++cc) {
        float xv = (cc & 1) ? hi16(vv[cc >> 1]) : lo16(vv[cc >> 1]);
        acc[cc] = fmaf(wf[cc], xv, acc[cc]);
      }
    }
  }
  if (act) {
#pragma unroll
    for (int cc = 0; cc < 8; ++cc) acc[cc] = acc[cc] / (1.f + __expf(-acc[cc]));
  }
  ushort4 s0, s1;
  s0.x = fbf(acc[0]); s0.y = fbf(acc[1]); s0.z = fbf(acc[2]); s0.w = fbf(acc[3]);
  s1.x = fbf(acc[4]); s1.y = fbf(acc[5]); s1.z = fbf(acc[6]); s1.w = fbf(acc[7]);
  u16* po = out + ((long)b << 21) + ((((h << 7) + w)) << 7) + c0;
  *(ushort4*)po = s0;
  *(ushort4*)(po + 4) = s1;
}

// ---- K3b: LN + GELU + MFMA offset projection; 64-pixel tile ----------------
// offs layout [b][g][l] float2
__global__ __launch_bounds__(256) void k_offset(const u16* __restrict__ x1,
                                                const float* __restrict__ g,
                                                const float* __restrict__ bt,
                                                const float* __restrict__ offw,
                                                const float* __restrict__ offb,
                                                float* __restrict__ offs) {
  __shared__ __align__(16) u16 Ge[64 * 136];   // [l][c] bf16: x1 then gelu
  __shared__ __align__(16) u16 Wos[16 * 136];  // [o][c] bf16
  __shared__ float ps[4][64], pss[4][64];
  __shared__ float mean_s[64], rstd_s[64];
  __shared__ float gs[128], bsh[128];
  int tid = threadIdx.x;
  int pg0 = blockIdx.x << 6;
  int b = pg0 >> 14;
  if (tid < 128) { gs[tid] = g[tid]; bsh[tid] = bt[tid]; }
  for (int i = 0; i < 8; ++i) {
    int idx = (i << 8) + tid;  // 2048 = 16o x 128c
    int o = idx >> 7, c = idx & 127;
    Wos[o * 136 + c] = fbf(offw[idx]);
  }
  int l = tid >> 2, cq = (tid & 3) << 5;
  {
    const u16* px = x1 + (((long)(pg0 + l)) << 7) + cq;
    float s = 0.f, ss = 0.f;
#pragma unroll
    for (int i2 = 0; i2 < 4; ++i2) {
      uint4 v = *(const uint4*)(px + (i2 << 3));
      *(uint4*)&Ge[l * 136 + cq + (i2 << 3)] = v;
      u32 vv[4] = {v.x, v.y, v.z, v.w};
#pragma unroll
      for (int cc = 0; cc < 8; ++cc) {
        float xv = (cc & 1) ? hi16(vv[cc >> 1]) : lo16(vv[cc >> 1]);
        s += xv; ss = fmaf(xv, xv, ss);
      }
    }
    ps[tid & 3][l] = s; pss[tid & 3][l] = ss;
  }
  __syncthreads();
  if (tid < 64) {
    float s = ps[0][tid] + ps[1][tid] + ps[2][tid] + ps[3][tid];
    float ss = pss[0][tid] + pss[1][tid] + pss[2][tid] + pss[3][tid];
    float m = s * (1.f / 128.f);
    mean_s[tid] = m;
    rstd_s[tid] = rsqrtf(ss * (1.f / 128.f) - m * m + 1e-6f);
  }
  __syncthreads();
  {
    float m = mean_s[l], r = rstd_s[l];
    u16* row = &Ge[l * 136 + cq];
#pragma unroll 8
    for (int cc = 0; cc < 32; ++cc) {
      int c = cq + cc;
      float v = bfu(row[cc]);
      float xn = fmaf((v - m) * r, gs[c], bsh[c]);
      row[cc] = fbf(0.5f * xn * (1.f + erff(xn * 0.70710678118f)));
    }
  }
  __syncthreads();
  int w = tid >> 6, lane = tid & 63;
  int mrow = lane & 15, quad = lane >> 4;
  f32x4 acc0 = (f32x4){0.f, 0.f, 0.f, 0.f};
#pragma unroll
  for (int kb = 0; kb < 4; ++kb) {
    int c0 = (kb << 5) + (quad << 3);
    bf16x8 af = ld_bf8(&Wos[mrow * 136 + c0]);
    bf16x8 bfr = ld_bf8(&Ge[((w << 4) + mrow) * 136 + c0]);
    acc0 = __builtin_amdgcn_mfma_f32_16x16x32_bf16(af, bfr, acc0, 0, 0, 0);
  }
  // D: col(lane&15)=l, row(quad*4+reg)=o.  o pairs (2g,2g+1): g0=2*quad, g1=2*quad+1
  int lg = (pg0 & 16383) + (w << 4) + mrow;
  float2* po = (float2*)offs;
  int o0 = quad << 2;
  po[(((long)((b << 3) + (quad << 1))) << 14) + lg] =
      make_float2(acc0[0] + offb[o0], acc0[1] + offb[o0 + 1]);
  po[(((long)((b << 3) + (quad << 1) + 1)) << 14) + lg] =
      make_float2(acc0[2] + offb[o0 + 2], acc0[3] + offb[o0 + 3]);
}

// ---- K4: DCN gather + x_proj + dt_w; 64-pixel tile, 512 thr, full-line IO --
__global__ __launch_bounds__(512) void k_dcn(const u16* __restrict__ xc,
                                             const float* __restrict__ offs,
                                             const float* __restrict__ xpw,
                                             const float* __restrict__ dtw,
                                             u16* __restrict__ xs,
                                             u16* __restrict__ dts,
                                             float* __restrict__ Bsb,
                                             float* __restrict__ Csb) {
  __shared__ float xds[64 * 129];   // [p][c]
  __shared__ float xdbl[64 * 13];   // [p][r]
  __shared__ float xpws[1280];
  __shared__ float dtws[1024];
  int tid = threadIdx.x;
  for (int i = 0; i < 3; ++i) { int idx = (i << 9) + tid; if (idx < 1280) xpws[idx] = xpw[idx]; }
  for (int i = 0; i < 2; ++i) { int idx = (i << 9) + tid; dtws[idx] = dtw[idx]; }
  int blk = blockIdx.x;
  int b = blk >> 8;
  int l0 = (blk & 255) << 6;
  int p = tid & 63, gg = tid >> 6;
  int l = l0 + p, hh = l >> 7, ww = l & 127;
  float2 off = ((const float2*)offs)[(((long)((b << 3) + gg)) << 14) + l];
  float px = (float)ww + off.x, py = (float)hh + off.y;
  float x0f = floorf(px), y0f = floorf(py);
  float wx = px - x0f, wy = py - y0f;
  int ix = (int)x0f, iy = (int)y0f;
  float acc[16];
#pragma unroll
  for (int ch = 0; ch < 16; ++ch) acc[ch] = 0.f;
  const u16* bbase = xc + ((long)b << 21) + (gg << 4);
  int xi[4] = {ix, ix + 1, ix, ix + 1};
  int yi[4] = {iy, iy, iy + 1, iy + 1};
  float wt4[4] = {(1.f - wy) * (1.f - wx), (1.f - wy) * wx, wy * (1.f - wx), wy * wx};
#pragma unroll
  for (int t = 0; t < 4; ++t) {
    if (wt4[t] != 0.f && (unsigned)yi[t] < 128u && (unsigned)xi[t] < 128u) {
      const u16* pp = bbase + ((((yi[t] << 7) + xi[t])) << 7);
      uint4 v0 = *(const uint4*)pp;
      uint4 v1 = *(const uint4*)(pp + 8);
      float wv = wt4[t];
      u32 vv[8] = {v0.x, v0.y, v0.z, v0.w, v1.x, v1.y, v1.z, v1.w};
#pragma unroll
      for (int ch = 0; ch < 16; ++ch) {
        float xv = (ch & 1) ? hi16(vv[ch >> 1]) : lo16(vv[ch >> 1]);
        acc[ch] = fmaf(wv, xv, acc[ch]);
      }
    }
  }
#pragma unroll
  for (int ch = 0; ch < 16; ++ch) xds[p * 129 + (gg << 4) + ch] = acc[ch];
  __syncthreads();
  // xs: 1024 tasks (128 c x 8 l-octets); 16B stores; per-wave full 128B lines
#pragma unroll
  for (int it = 0; it < 2; ++it) {
    int task = (it << 9) + tid;
    int cc = task >> 3, t = task & 7;
    u32 pk[4];
#pragma unroll
    for (int jj = 0; jj < 4; ++jj) {
      u16 a0 = fbf(xds[((t << 3) + 2 * jj + 0) * 129 + cc]);
      u16 a1 = fbf(xds[((t << 3) + 2 * jj + 1) * 129 + cc]);
      pk[jj] = (u32)a0 | ((u32)a1 << 16);
    }
    *(uint4*)&xs[(((long)(b << 7) + cc) << 14) + l0 + (t << 3)] =
        make_uint4(pk[0], pk[1], pk[2], pk[3]);
  }
  for (int task = tid; task < 640; task += 512) {
    int p2 = task / 10, r = task - p2 * 10;
    const float* wr = xpws + (r << 7);
    const float* xr = xds + p2 * 129;
    float sacc = 0.f;
#pragma unroll 8
    for (int cc = 0; cc < 128; ++cc) sacc = fmaf(wr[cc], xr[cc], sacc);
    xdbl[p2 * 13 + r] = sacc;
  }
  __syncthreads();
  // dts: 1024 tasks (128 d x 8 l-octets); 16B stores
#pragma unroll
  for (int it = 0; it < 2; ++it) {
    int task = (it << 9) + tid;
    int dd = task >> 3, t = task & 7;
    const float* wd = dtws + (dd << 3);
    u32 pk[4];
#pragma unroll
    for (int jj = 0; jj < 4; ++jj) {
      u16 h2[2];
#pragma unroll
      for (int hh2 = 0; hh2 < 2; ++hh2) {
        const float* xb = xdbl + ((t << 3) + 2 * jj + hh2) * 13;
        float sacc = 0.f;
#pragma unroll
        for (int r = 0; r < 8; ++r) sacc = fmaf(wd[r], xb[r], sacc);
        h2[hh2] = fbf(sacc);
      }
      pk[jj] = (u32)h2[0] | ((u32)h2[1] << 16);
    }
    *(uint4*)&dts[(((long)(b << 7) + dd) << 14) + l0 + (t << 3)] =
        make_uint4(pk[0], pk[1], pk[2], pk[3]);
  }
  if (tid < 64) {
    Bsb[((long)b << 14) + l0 + tid] = xdbl[tid * 13 + 8];
    Csb[((long)b << 14) + l0 + tid] = xdbl[tid * 13 + 9];
  }
}

// ---- K5: selective scan, shfl-based block scan, cheap softplus -------------
__global__ __launch_bounds__(1024) void k_scan(u16* __restrict__ xy,
                                               const u16* __restrict__ dts16,
                                               const float* __restrict__ Bsb,
                                               const float* __restrict__ Csb,
                                               const float* __restrict__ A_logs,
                                               const float* __restrict__ Dsv,
                                               const float* __restrict__ dtbv) {
  __shared__ float swp[16], swe[16];
  int bd = blockIdx.x;
  int b = bd >> 7, d = bd & 127;
  float Ad = -__expf(A_logs[d]);
  float dtb = dtbv[d];
  float Dd = Dsv[d];
  int t = threadIdx.x;
  int lane = t & 63, wid = t >> 6;
  long base = ((long)bd << 14) + (t << 4);
  long bb = ((long)b << 14) + (t << 4);
  const uint4* pz4 = (const uint4*)(dts16 + base);
  const uint4* px4 = (const uint4*)(xy + base);
  const float4* pB = (const float4*)(Bsb + bb);
  const float4* pC = (const float4*)(Csb + bb);
  uint4 zA = pz4[0], zB = pz4[1];
  uint4 xA = px4[0], xB = px4[1];
  u32 zw[8] = {zA.x, zA.y, zA.z, zA.w, zB.x, zB.y, zB.z, zB.w};
  u32 xw[8] = {xA.x, xA.y, xA.z, xA.w, xB.x, xB.y, xB.z, xB.w};
  float E = 0.f, P = 1.f;
#pragma unroll
  for (int q = 0; q < 4; ++q) {
    float4 B4 = pB[q];
    float Bq[4] = {B4.x, B4.y, B4.z, B4.w};
#pragma unroll
    for (int j = 0; j < 4; ++j) {
      int k = (q << 2) + j;
      float z = (k & 1) ? hi16(zw[k >> 1]) : lo16(zw[k >> 1]);
      float xv = (k & 1) ? hi16(xw[k >> 1]) : lo16(xw[k >> 1]);
      float delta = softplusf(z + dtb);
      float a = __expf(delta * Ad);
      E = fmaf(a, E, delta * Bq[j] * xv);
      P *= a;
    }
  }
#pragma unroll
  for (int off = 1; off < 64; off <<= 1) {
    float Pp = __shfl_up(P, off);
    float Ep = __shfl_up(E, off);
    if (lane >= off) { E = fmaf(P, Ep, E); P *= Pp; }
  }
  if (lane == 63) { swp[wid] = P; swe[wid] = E; }
  __syncthreads();
  if (t < 16) {
    float p2 = swp[t], e2 = swe[t];
#pragma unroll
    for (int off = 1; off < 16; off <<= 1) {
      float pp = __shfl_up(p2, off);
      float ee = __shfl_up(e2, off);
      if (t >= off) { e2 = fmaf(p2, ee, e2); p2 *= pp; }
    }
    swp[t] = p2; swe[t] = e2;
  }
  __syncthreads();
  float hw = (wid == 0) ? 0.f : swe[wid - 1];
  float Pex = __shfl_up(P, 1);
  float Eex = __shfl_up(E, 1);
  if (lane == 0) { Pex = 1.f; Eex = 0.f; }
  float h = fmaf(Pex, hw, Eex);
  u32 ypk[8];
#pragma unroll
  for (int q = 0; q < 4; ++q) {
    float4 B4 = pB[q];
    float4 C4 = pC[q];
    float Bq[4] = {B4.x, B4.y, B4.z, B4.w};
    float Cq[4] = {C4.x, C4.y, C4.z, C4.w};
#pragma unroll
    for (int j = 0; j < 4; ++j) {
      int k = (q << 2) + j;
      float z = (k & 1) ? hi16(zw[k >> 1]) : lo16(zw[k >> 1]);
      float xv = (k & 1) ? hi16(xw[k >> 1]) : lo16(xw[k >> 1]);
      float delta = softplusf(z + dtb);
      float a = __expf(delta * Ad);
      h = fmaf(a, h, delta * Bq[j] * xv);
      u16 yb = fbf(fmaf(Dd, xv, h * Cq[j]));
      if ((k & 1) == 0) ypk[k >> 1] = yb; else ypk[k >> 1] |= (u32)yb << 16;
    }
  }
  uint4* py = (uint4*)(xy + base);
  py[0] = make_uint4(ypk[0], ypk[1], ypk[2], ypk[3]);
  py[1] = make_uint4(ypk[4], ypk[5], ypk[6], ypk[7]);
}

// ---- K6b: s1[o]=sum W2*beta, s2[o]=sum W2*gamma ----------------------------
__global__ void k_sums(const float* __restrict__ W2, const float* __restrict__ g,
                       const float* __restrict__ bln, float* __restrict__ s12) {
  int o = threadIdx.x;
  float s1 = 0.f, s2 = 0.f;
  for (int c = 0; c < 128; ++c) {
    float w = W2[(o << 7) + c];
    s1 = fmaf(w, bln[c], s1);
    s2 = fmaf(w, g[c], s2);
  }
  s12[o] = s1;
  s12[128 + o] = s2;
}

// ---- K7: out_proj MFMA GEMM + fused LN epilogue (f32 out, [b,o,l]) ---------
__global__ __launch_bounds__(256) void k_outproj(const u16* __restrict__ y,
                                                 const float* __restrict__ W2,
                                                 const float* __restrict__ g,
                                                 const float* __restrict__ s12,
                                                 float* __restrict__ out) {
  __shared__ __align__(16) u16 Ws[128 * 136];  // [o][c] bf16 of W2*gamma
  __shared__ __align__(16) u16 Ys[64 * 136];   // [l][c] bf16 (y^T tile)
  __shared__ float ps[4][64], pss[4][64];
  __shared__ float mean_s[64], rstd_s[64];
  int tid = threadIdx.x;
  int b = blockIdx.x >> 8;
  int l0 = (blockIdx.x & 255) << 6;
  for (int i = 0; i < 16; ++i) {
    int idx = (i << 8) + tid;
    int o = idx >> 5, c4 = (idx & 31) << 2;
    float4 w4 = *(const float4*)&W2[(o << 7) + c4];
    ushort4 s;
    s.x = fbf(w4.x * g[c4]);     s.y = fbf(w4.y * g[c4 + 1]);
    s.z = fbf(w4.z * g[c4 + 2]); s.w = fbf(w4.w * g[c4 + 3]);
    *(ushort4*)&Ws[o * 136 + c4] = s;
  }
  for (int i = 0; i < 4; ++i) {
    int idx = (i << 8) + tid;
    int c = idx >> 3, lq = (idx & 7) << 3;
    uint4 v = *(const uint4*)&y[(((long)(b << 7) + c) << 14) + l0 + lq];
    u32 vv[4] = {v.x, v.y, v.z, v.w};
#pragma unroll
    for (int r = 0; r < 8; ++r)
      Ys[(lq + r) * 136 + c] = (u16)((r & 1) ? (vv[r >> 1] >> 16) : (vv[r >> 1] & 0xffffu));
  }
  __syncthreads();
  {
    int l = tid & 63, q = tid >> 6;
    const u16* row = &Ys[l * 136 + (q << 5)];
    float s = 0.f, ss = 0.f;
#pragma unroll 8
    for (int c = 0; c < 32; ++c) { float v = bfu(row[c]); s += v; ss = fmaf(v, v, ss); }
    ps[q][l] = s; pss[q][l] = ss;
  }
  __syncthreads();
  if (tid < 64) {
    float s = ps[0][tid] + ps[1][tid] + ps[2][tid] + ps[3][tid];
    float ss = pss[0][tid] + pss[1][tid] + pss[2][tid] + pss[3][tid];
    float m = s * (1.f / 128.f);
    mean_s[tid] = m;
    rstd_s[tid] = rsqrtf(ss * (1.f / 128.f) - m * m + 1e-6f);
  }
  __syncthreads();
  int w = tid >> 6, lane = tid & 63;
  int mrow = lane & 15, quad = lane >> 4;
  f32x4 acc[2][4];
#pragma unroll
  for (int ot = 0; ot < 2; ++ot)
#pragma unroll
    for (int lt = 0; lt < 4; ++lt) acc[ot][lt] = (f32x4){0.f, 0.f, 0.f, 0.f};
#pragma unroll
  for (int kb = 0; kb < 4; ++kb) {
    int c0 = (kb << 5) + (quad << 3);
    bf16x8 af[2], bfr[4];
#pragma unroll
    for (int ot = 0; ot < 2; ++ot)
      af[ot] = ld_bf8(&Ws[((w << 5) + (ot << 4) + mrow) * 136 + c0]);
#pragma unroll
    for (int lt = 0; lt < 4; ++lt)
      bfr[lt] = ld_bf8(&Ys[((lt << 4) + mrow) * 136 + c0]);
#pragma unroll
    for (int ot = 0; ot < 2; ++ot)
#pragma unroll
      for (int lt = 0; lt < 4; ++lt)
        acc[ot][lt] = __builtin_amdgcn_mfma_f32_16x16x32_bf16(af[ot], bfr[lt], acc[ot][lt], 0, 0, 0);
  }
  float s1r[2][4], s2r[2][4];
#pragma unroll
  for (int ot = 0; ot < 2; ++ot)
#pragma unroll
    for (int r = 0; r < 4; ++r) {
      int o = (w << 5) + (ot << 4) + (quad << 2) + r;
      s1r[ot][r] = s12[o];
      s2r[ot][r] = s12[128 + o];
    }
#pragma unroll
  for (int ot = 0; ot < 2; ++ot)
#pragma unroll
    for (int lt = 0; lt < 4; ++lt) {
      int lcol = (lt << 4) + mrow;
      float mv = mean_s[lcol], rv = rstd_s[lcol];
      int obase = (w << 5) + (ot << 4) + (quad << 2);
#pragma unroll
      for (int r = 0; r < 4; ++r) {
        float v = fmaf(rv, acc[ot][lt][r] - mv * s2r[ot][r], s1r[ot][r]);
        out[(((long)(b << 7) + obase + r) << 14) + l0 + lcol] = v;
      }
    }
}

extern "C" void kernel_launch(void* const* d_in, const int* in_sizes, int n_in,
                              void* d_out, int out_size, void* d_ws, size_t ws_size,
                              hipStream_t stream) {
  const float* x         = (const float*)d_in[0];
  const float* in_proj_w = (const float*)d_in[1];
  const float* conv2d_w  = (const float*)d_in[2];
  const float* conv2d_b  = (const float*)d_in[3];
  const float* dw_w      = (const float*)d_in[4];
  const float* dw_b      = (const float*)d_in[5];
  const float* dw_ln_g   = (const float*)d_in[6];
  const float* dw_ln_b   = (const float*)d_in[7];
  const float* off_w     = (const float*)d_in[8];
  const float* off_b     = (const float*)d_in[9];
  const float* x_proj_w  = (const float*)d_in[10];
  const float* dt_w      = (const float*)d_in[11];
  const float* dt_b      = (const float*)d_in[12];
  const float* A_logs    = (const float*)d_in[13];
  const float* Ds        = (const float*)d_in[14];
  const float* out_ln_g  = (const float*)d_in[15];
  const float* out_ln_b  = (const float*)d_in[16];
  const float* out_proj_w= (const float*)d_in[17];
  float* out = (float*)d_out;

  u16* A  = (u16*)d_ws;            // xin_cl -> x1_cl -> xs[b,c,l] -> y[b,c,l]
  u16* Bx = A + 8388608;           // xc_cl
  u16* Dd = Bx + 8388608;          // dts[b,c,l]
  float* offs  = (float*)(Dd + 8388608);  // [b][g][l] float2
  float* Bsb   = offs + 1048576;
  float* Csb   = Bsb + 65536;
  float* s12   = Csb + 65536;

  hipLaunchKernelGGL(k_inproj, dim3(1024), dim3(256), 0, stream, x, in_proj_w, A);
  hipLaunchKernelGGL(k_dwconv, dim3(4096), dim3(256), 0, stream, A, conv2d_w, conv2d_b, Bx, 1);
  hipLaunchKernelGGL(k_dwconv, dim3(4096), dim3(256), 0, stream, Bx, dw_w, dw_b, A, 0);
  hipLaunchKernelGGL(k_offset, dim3(1024), dim3(256), 0, stream, A, dw_ln_g, dw_ln_b, off_w, off_b, offs);
  hipLaunchKernelGGL(k_dcn, dim3(1024), dim3(512), 0, stream, Bx, offs, x_proj_w, dt_w, A, Dd, Bsb, Csb);
  hipLaunchKernelGGL(k_scan, dim3(512), dim3(1024), 0, stream, A, Dd, Bsb, Csb, A_logs, Ds, dt_b);
  hipLaunchKernelGGL(k_sums, dim3(1), dim3(128), 0, stream, out_proj_w, out_ln_g, out_ln_b, s12);
  hipLaunchKernelGGL(k_outproj, dim3(1024), dim3(256), 0, stream, A, out_proj_w, out_ln_g, s12, out);
}